// Round 2
// baseline (320.104 us; speedup 1.0000x reference)
//
#include <hip/hip_runtime.h>

typedef unsigned short ushort_t;
typedef unsigned int uint_t;
typedef short bhalf8 __attribute__((ext_vector_type(8)));
typedef float f32x4 __attribute__((ext_vector_type(4)));

#define S_NODES 16384
#define D_NODES 16384

__device__ __forceinline__ float b2f(ushort_t u) {
    union { uint_t i; float f; } v; v.i = ((uint_t)u) << 16; return v.f;
}
__device__ __forceinline__ ushort_t f2b(float f) {
    union { float f; uint_t i; } v; v.f = f;
    uint_t r = v.i + 0x7fffu + ((v.i >> 16) & 1u);
    return (ushort_t)(r >> 16);
}

// ---------------------------------------------------------------------------
// Weight pre-transform fp32 -> MFMA B-fragment bf16 order:
// out[((nt*KS + ks)*64 + lane)*8 + j] = W[(ks*32 + (lane>>4)*8 + j)*128 + nt*16 + (lane&15)]
// blocks 0-7: src_w, 8-15: dst_w, 16-23: w2, 24-31: out_w, 32-55: w1 (KS=12)
// ---------------------------------------------------------------------------
__global__ __launch_bounds__(256) void transform_weights(
    const float* __restrict__ wsrc, const float* __restrict__ wdst,
    const float* __restrict__ w2,   const float* __restrict__ wout,
    const float* __restrict__ w1,
    ushort_t* __restrict__ msrc, ushort_t* __restrict__ mdst,
    ushort_t* __restrict__ m2,   ushort_t* __restrict__ mout,
    ushort_t* __restrict__ m1)
{
    int b = blockIdx.x, tid = threadIdx.x;
    const float* in; ushort_t* out; int KS; int flat;
    if (b < 8)       { in = wsrc; out = msrc; KS = 4;  flat = b*256 + tid; }
    else if (b < 16) { in = wdst; out = mdst; KS = 4;  flat = (b-8)*256 + tid; }
    else if (b < 24) { in = w2;   out = m2;   KS = 4;  flat = (b-16)*256 + tid; }
    else if (b < 32) { in = wout; out = mout; KS = 4;  flat = (b-24)*256 + tid; }
    else             { in = w1;   out = m1;   KS = 12; flat = (b-32)*256 + tid; }
    int nt = flat / (KS*64);
    int rem = flat % (KS*64);
    int ks = rem >> 6, lane = rem & 63;
    int q = lane >> 4, m = lane & 15;
    #pragma unroll
    for (int j = 0; j < 8; ++j)
        out[flat*8 + j] = f2b(in[(ks*32 + q*8 + j)*128 + nt*16 + m]);
}

// ---------------------------------------------------------------------------
// enc = relu(A_f32 @ W + bias) -> bf16. 64 rows/block, 4 waves.
// ---------------------------------------------------------------------------
__global__ __launch_bounds__(256) void enc_kernel(
    const float* __restrict__ A, const ushort_t* __restrict__ Wm,
    const float* __restrict__ bias, ushort_t* __restrict__ out)
{
    __shared__ ushort_t A_l[64*136];   // bf16, pad 128->136
    __shared__ float b_l[128];
    int tid = threadIdx.x, blk = blockIdx.x;

    const float4* A4 = (const float4*)A;
    for (int i = tid; i < 2048; i += 256) {          // 64 rows x 32 float4
        int r = i >> 5, c = i & 31;
        float4 v = A4[(size_t)(blk*64 + r)*32 + c];
        uint2 u;
        u.x = (uint_t)f2b(v.x) | ((uint_t)f2b(v.y) << 16);
        u.y = (uint_t)f2b(v.z) | ((uint_t)f2b(v.w) << 16);
        *(uint2*)(A_l + r*136 + c*4) = u;
    }
    if (tid < 128) b_l[tid] = bias[tid];
    __syncthreads();

    int lane = tid & 63, w = tid >> 6, q = lane >> 4, m = lane & 15;
    f32x4 acc[4][2] = {};
    const bhalf8* Wv = (const bhalf8*)Wm;
    #pragma unroll
    for (int ks = 0; ks < 4; ++ks) {
        bhalf8 bf0 = Wv[((2*w)*4 + ks)*64 + lane];
        bhalf8 bf1 = Wv[((2*w+1)*4 + ks)*64 + lane];
        #pragma unroll
        for (int mt = 0; mt < 4; ++mt) {
            bhalf8 a = *(const bhalf8*)(A_l + (mt*16 + m)*136 + ks*32 + q*8);
            acc[mt][0] = __builtin_amdgcn_mfma_f32_16x16x32_bf16(a, bf0, acc[mt][0], 0, 0, 0);
            acc[mt][1] = __builtin_amdgcn_mfma_f32_16x16x32_bf16(a, bf1, acc[mt][1], 0, 0, 0);
        }
    }
    #pragma unroll
    for (int mt = 0; mt < 4; ++mt)
    #pragma unroll
    for (int nt = 0; nt < 2; ++nt)
    #pragma unroll
    for (int reg = 0; reg < 4; ++reg) {
        int col = w*32 + nt*16 + m;
        size_t row = (size_t)blk*64 + mt*16 + q*4 + reg;
        out[row*128 + col] = f2b(fmaxf(acc[mt][nt][reg] + b_l[col], 0.f));
    }
}

// ---------------------------------------------------------------------------
// out_f32 = relu(A_bf16 @ W + bias + resid_f32)
// ---------------------------------------------------------------------------
__global__ __launch_bounds__(256) void final_kernel(
    const ushort_t* __restrict__ A, const ushort_t* __restrict__ Wm,
    const float* __restrict__ bias, const float* __restrict__ resid,
    float* __restrict__ out)
{
    __shared__ ushort_t A_l[64*136];
    __shared__ float b_l[128];
    int tid = threadIdx.x, blk = blockIdx.x;

    const uint4* A4 = (const uint4*)A;
    for (int i = tid; i < 1024; i += 256) {          // 64 rows x 16 uint4 (8 bf16)
        int r = i >> 4, c = i & 15;
        *(uint4*)(A_l + r*136 + c*8) = A4[(size_t)(blk*64 + r)*16 + c];
    }
    if (tid < 128) b_l[tid] = bias[tid];
    __syncthreads();

    int lane = tid & 63, w = tid >> 6, q = lane >> 4, m = lane & 15;
    f32x4 acc[4][2] = {};
    const bhalf8* Wv = (const bhalf8*)Wm;
    #pragma unroll
    for (int ks = 0; ks < 4; ++ks) {
        bhalf8 bf0 = Wv[((2*w)*4 + ks)*64 + lane];
        bhalf8 bf1 = Wv[((2*w+1)*4 + ks)*64 + lane];
        #pragma unroll
        for (int mt = 0; mt < 4; ++mt) {
            bhalf8 a = *(const bhalf8*)(A_l + (mt*16 + m)*136 + ks*32 + q*8);
            acc[mt][0] = __builtin_amdgcn_mfma_f32_16x16x32_bf16(a, bf0, acc[mt][0], 0, 0, 0);
            acc[mt][1] = __builtin_amdgcn_mfma_f32_16x16x32_bf16(a, bf1, acc[mt][1], 0, 0, 0);
        }
    }
    #pragma unroll
    for (int mt = 0; mt < 4; ++mt)
    #pragma unroll
    for (int nt = 0; nt < 2; ++nt)
    #pragma unroll
    for (int reg = 0; reg < 4; ++reg) {
        int col = w*32 + nt*16 + m;
        size_t row = (size_t)blk*64 + mt*16 + q*4 + reg;
        float v = acc[mt][nt][reg] + b_l[col] + resid[row*128 + col];
        out[row*128 + col] = fmaxf(v, 0.f);
    }
}

// ---------------------------------------------------------------------------
// CSR build: count, scan (single block), fill
// ---------------------------------------------------------------------------
__global__ __launch_bounds__(256) void count_deg(const int* __restrict__ edi, int E,
                                                 int* __restrict__ deg)
{
    int i = blockIdx.x*256 + threadIdx.x;
    if (i < E) atomicAdd(&deg[edi[i]], 1);
}

__global__ __launch_bounds__(256) void scan_deg(const int* __restrict__ deg,
                                                int* __restrict__ nxt)
{
    __shared__ int sums[256];
    int t = threadIdx.x;
    int base = t*64;
    int s = 0;
    for (int i = 0; i < 64; ++i) s += deg[base + i];
    sums[t] = s;
    __syncthreads();
    for (int off = 1; off < 256; off <<= 1) {
        int v = (t >= off) ? sums[t - off] : 0;
        __syncthreads();
        sums[t] += v;
        __syncthreads();
    }
    int run = sums[t] - s;   // exclusive prefix
    for (int i = 0; i < 64; ++i) { nxt[base + i] = run; run += deg[base + i]; }
}

__global__ __launch_bounds__(256) void fill_order(const int* __restrict__ edi, int E,
                                                  int* __restrict__ nxt,
                                                  int* __restrict__ order)
{
    int i = blockIdx.x*256 + threadIdx.x;
    if (i < E) {
        int p = atomicAdd(&nxt[edi[i]], 1);
        order[p] = i;
    }
}

// ---------------------------------------------------------------------------
// Edge kernel: 64 dst-sorted edges/block.
// X = [src_enc | relu(dpos@dist_w+db) | dst_enc] bf16 in LDS -> GEMM1 -> relu
// -> run-segmented atomic scatter into hsum (f32).
// ---------------------------------------------------------------------------
__global__ __launch_bounds__(256) void edge_kernel(
    const ushort_t* __restrict__ src_enc, const ushort_t* __restrict__ dst_enc,
    const float* __restrict__ src_pos, const float* __restrict__ dst_pos,
    const int* __restrict__ esi, const int* __restrict__ edi,
    const int* __restrict__ order, int E,
    const ushort_t* __restrict__ w1m, const float* __restrict__ eb1,
    const float* __restrict__ dist_w, const float* __restrict__ dist_b,
    float* __restrict__ hsum)
{
    __shared__ char xbuf[64*392*2];           // X bf16 [64][392] aliased with H f32 [64][132]
    __shared__ int es_l[64], ed_l[64];
    __shared__ float dx_l[64], dy_l[64];
    __shared__ float b1_l[128], dw0_l[128], dw1_l[128], db_l[128];

    ushort_t* X = (ushort_t*)xbuf;
    float* H = (float*)xbuf;

    int tid = threadIdx.x, blk = blockIdx.x;

    if (tid < 64) {
        int slot = blk*64 + tid;
        if (slot < E) {
            int e = order[slot];
            int s = esi[e], d = edi[e];
            es_l[tid] = s; ed_l[tid] = d;
            float2 sp = ((const float2*)src_pos)[s];
            float2 dp = ((const float2*)dst_pos)[d];
            dx_l[tid] = sp.x - dp.x;
            dy_l[tid] = sp.y - dp.y;
        } else {
            es_l[tid] = 0; ed_l[tid] = 0x7fffffff; dx_l[tid] = 0.f; dy_l[tid] = 0.f;
        }
    }
    if (tid < 128) {
        b1_l[tid]  = eb1[tid];
        dw0_l[tid] = dist_w[tid];
        dw1_l[tid] = dist_w[128 + tid];
        db_l[tid]  = dist_b[tid];
    }
    __syncthreads();

    const uint4* se4 = (const uint4*)src_enc;
    const uint4* de4 = (const uint4*)dst_enc;
    for (int i = tid; i < 1024; i += 256) {          // e_src -> cols [0,128)
        int r = i >> 4, c = i & 15;
        *(uint4*)(X + r*392 + c*8) = se4[(size_t)es_l[r]*16 + c];
    }
    for (int i = tid; i < 1024; i += 256) {          // e_dst -> cols [256,384)
        int r = i >> 4, c = i & 15;
        int dg = ed_l[r]; if (dg == 0x7fffffff) dg = 0;
        *(uint4*)(X + r*392 + 256 + c*8) = de4[(size_t)dg*16 + c];
    }
    for (int i = tid; i < 8192; i += 256) {          // e_dist -> cols [128,256)
        int r = i >> 7, j = i & 127;
        float v = dx_l[r]*dw0_l[j] + dy_l[r]*dw1_l[j] + db_l[j];
        X[r*392 + 128 + j] = f2b(fmaxf(v, 0.f));
    }
    __syncthreads();

    int lane = tid & 63, w = tid >> 6, q = lane >> 4, m = lane & 15;
    f32x4 acc[4][2] = {};
    const bhalf8* Wv = (const bhalf8*)w1m;
    #pragma unroll
    for (int ks = 0; ks < 12; ++ks) {
        bhalf8 bf0 = Wv[((2*w)*12 + ks)*64 + lane];
        bhalf8 bf1 = Wv[((2*w+1)*12 + ks)*64 + lane];
        #pragma unroll
        for (int mt = 0; mt < 4; ++mt) {
            bhalf8 a = *(const bhalf8*)(X + (mt*16 + m)*392 + ks*32 + q*8);
            acc[mt][0] = __builtin_amdgcn_mfma_f32_16x16x32_bf16(a, bf0, acc[mt][0], 0, 0, 0);
            acc[mt][1] = __builtin_amdgcn_mfma_f32_16x16x32_bf16(a, bf1, acc[mt][1], 0, 0, 0);
        }
    }
    __syncthreads();   // all X reads done before H overwrites the buffer

    #pragma unroll
    for (int mt = 0; mt < 4; ++mt)
    #pragma unroll
    for (int nt = 0; nt < 2; ++nt)
    #pragma unroll
    for (int reg = 0; reg < 4; ++reg) {
        int col = w*32 + nt*16 + m;
        int row = mt*16 + q*4 + reg;
        H[row*132 + col] = fmaxf(acc[mt][nt][reg] + b1_l[col], 0.f);
    }
    __syncthreads();

    // run-segmented reduction over the dst-sorted tile, one atomic per (run, col)
    if (tid < 128) {
        int j = tid;
        float a = 0.f;
        for (int r = 0; r < 64; ++r) {
            a += H[r*132 + j];
            int dcur = ed_l[r];
            bool bnd = (r == 63) || (ed_l[r + 1] != dcur);
            if (bnd) {
                if (dcur != 0x7fffffff) atomicAdd(&hsum[(size_t)dcur*128 + j], a);
                a = 0.f;
            }
        }
    }
}

// ---------------------------------------------------------------------------
// agg = dst_enc + hsum@W2 + deg*b2 ; LayerNorm ; relu -> act (bf16)
// ---------------------------------------------------------------------------
__global__ __launch_bounds__(256) void agg_ln(
    const float* __restrict__ hsum, const ushort_t* __restrict__ w2m,
    const float* __restrict__ b2, const int* __restrict__ deg,
    const ushort_t* __restrict__ dst_enc, const float* __restrict__ ln_g,
    const float* __restrict__ ln_b, ushort_t* __restrict__ act)
{
    __shared__ char buf[64*132*4];  // A_l bf16 [64][136] aliased with Y f32 [64][132]
    __shared__ float b2_l[128], g_l[128], bl_l[128];
    __shared__ int deg_l[64];
    __shared__ float ps[64][4], ps2[64][4], mu_l[64], inv_l[64];

    ushort_t* A_l = (ushort_t*)buf;
    float* Y = (float*)buf;
    int tid = threadIdx.x, blk = blockIdx.x;

    const float4* hv = (const float4*)hsum;
    for (int i = tid; i < 1024; i += 256) {
        int r = i >> 4, c = i & 15;
        size_t base = (size_t)(blk*64 + r)*32 + c*2;
        float4 p0 = hv[base], p1 = hv[base + 1];
        uint4 u;
        u.x = (uint_t)f2b(p0.x) | ((uint_t)f2b(p0.y) << 16);
        u.y = (uint_t)f2b(p0.z) | ((uint_t)f2b(p0.w) << 16);
        u.z = (uint_t)f2b(p1.x) | ((uint_t)f2b(p1.y) << 16);
        u.w = (uint_t)f2b(p1.z) | ((uint_t)f2b(p1.w) << 16);
        *(uint4*)(A_l + r*136 + c*8) = u;
    }
    if (tid < 128) { b2_l[tid] = b2[tid]; g_l[tid] = ln_g[tid]; bl_l[tid] = ln_b[tid]; }
    if (tid < 64) deg_l[tid] = deg[blk*64 + tid];
    __syncthreads();

    int lane = tid & 63, w = tid >> 6, q = lane >> 4, m = lane & 15;
    f32x4 acc[4][2] = {};
    const bhalf8* Wv = (const bhalf8*)w2m;
    #pragma unroll
    for (int ks = 0; ks < 4; ++ks) {
        bhalf8 bf0 = Wv[((2*w)*4 + ks)*64 + lane];
        bhalf8 bf1 = Wv[((2*w+1)*4 + ks)*64 + lane];
        #pragma unroll
        for (int mt = 0; mt < 4; ++mt) {
            bhalf8 a = *(const bhalf8*)(A_l + (mt*16 + m)*136 + ks*32 + q*8);
            acc[mt][0] = __builtin_amdgcn_mfma_f32_16x16x32_bf16(a, bf0, acc[mt][0], 0, 0, 0);
            acc[mt][1] = __builtin_amdgcn_mfma_f32_16x16x32_bf16(a, bf1, acc[mt][1], 0, 0, 0);
        }
    }
    __syncthreads();   // A_l reads done before Y overwrites

    #pragma unroll
    for (int mt = 0; mt < 4; ++mt)
    #pragma unroll
    for (int nt = 0; nt < 2; ++nt)
    #pragma unroll
    for (int reg = 0; reg < 4; ++reg) {
        int col = w*32 + nt*16 + m;
        int rowl = mt*16 + q*4 + reg;
        size_t grow = (size_t)blk*64 + rowl;
        float v = acc[mt][nt][reg] + (float)deg_l[rowl]*b2_l[col] + b2f(dst_enc[grow*128 + col]);
        Y[rowl*132 + col] = v;
    }
    __syncthreads();

    {
        int r = tid >> 2, t4 = tid & 3;
        float s = 0.f, s2 = 0.f;
        for (int jj = 0; jj < 32; ++jj) {
            float v = Y[r*132 + t4*32 + jj];
            s += v; s2 += v*v;
        }
        ps[r][t4] = s; ps2[r][t4] = s2;
    }
    __syncthreads();
    if (tid < 64) {
        int r = tid;
        float sum = ps[r][0] + ps[r][1] + ps[r][2] + ps[r][3];
        float sum2 = ps2[r][0] + ps2[r][1] + ps2[r][2] + ps2[r][3];
        float mu = sum / 128.f;
        float var = sum2 / 128.f - mu*mu;
        mu_l[r] = mu;
        inv_l[r] = 1.0f / sqrtf(var + 1e-5f);
    }
    __syncthreads();
    for (int i = tid; i < 8192; i += 256) {
        int r = i >> 7, j = i & 127;
        float v = (Y[r*132 + j] - mu_l[r]) * inv_l[r] * g_l[j] + bl_l[j];
        act[(size_t)(blk*64 + r)*128 + j] = f2b(fmaxf(v, 0.f));
    }
}

// ---------------------------------------------------------------------------
extern "C" void kernel_launch(void* const* d_in, const int* in_sizes, int n_in,
                              void* d_out, int out_size, void* d_ws, size_t ws_size,
                              hipStream_t stream)
{
    const float* src_feat = (const float*)d_in[0];
    const float* src_pos  = (const float*)d_in[1];
    const float* dst_feat = (const float*)d_in[2];
    const float* dst_pos  = (const float*)d_in[3];
    const float* src_w    = (const float*)d_in[4];
    const float* src_b    = (const float*)d_in[5];
    const float* dst_w    = (const float*)d_in[6];
    const float* dst_b    = (const float*)d_in[7];
    const float* dist_w   = (const float*)d_in[8];
    const float* dist_b   = (const float*)d_in[9];
    const float* w1       = (const float*)d_in[10];
    const float* b1       = (const float*)d_in[11];
    const float* w2       = (const float*)d_in[12];
    const float* b2       = (const float*)d_in[13];
    const float* ln_g     = (const float*)d_in[14];
    const float* ln_b     = (const float*)d_in[15];
    const float* out_w    = (const float*)d_in[16];
    const float* out_b    = (const float*)d_in[17];
    const int* esi        = (const int*)d_in[18];
    const int* edi        = (const int*)d_in[19];
    int E = in_sizes[18];

    char* ws = (char*)d_ws;
    size_t off = 0;
    auto alloc = [&](size_t bytes) { char* p = ws + off; off += (bytes + 511) & ~(size_t)511; return p; };
    ushort_t* src_enc = (ushort_t*)alloc((size_t)S_NODES*128*2);
    ushort_t* dst_enc = (ushort_t*)alloc((size_t)D_NODES*128*2);
    float*    hsum    = (float*)   alloc((size_t)D_NODES*128*4);
    ushort_t* act     = (ushort_t*)alloc((size_t)D_NODES*128*2);
    ushort_t* m1      = (ushort_t*)alloc(384*128*2);
    ushort_t* msrc    = (ushort_t*)alloc(128*128*2);
    ushort_t* mdst    = (ushort_t*)alloc(128*128*2);
    ushort_t* m2      = (ushort_t*)alloc(128*128*2);
    ushort_t* mout    = (ushort_t*)alloc(128*128*2);
    int*      deg     = (int*)     alloc((size_t)D_NODES*4);
    int*      nxt     = (int*)     alloc((size_t)D_NODES*4);
    int*      order   = (int*)     alloc((size_t)E*4);

    hipMemsetAsync(hsum, 0, (size_t)D_NODES*128*4, stream);
    hipMemsetAsync(deg, 0, (size_t)D_NODES*4, stream);

    transform_weights<<<56, 256, 0, stream>>>(src_w, dst_w, w2, out_w, w1,
                                              msrc, mdst, m2, mout, m1);
    enc_kernel<<<S_NODES/64, 256, 0, stream>>>(src_feat, msrc, src_b, src_enc);
    enc_kernel<<<D_NODES/64, 256, 0, stream>>>(dst_feat, mdst, dst_b, dst_enc);
    count_deg<<<(E + 255)/256, 256, 0, stream>>>(edi, E, deg);
    scan_deg<<<1, 256, 0, stream>>>(deg, nxt);
    fill_order<<<(E + 255)/256, 256, 0, stream>>>(edi, E, nxt, order);
    edge_kernel<<<(E + 63)/64, 256, 0, stream>>>(src_enc, dst_enc, src_pos, dst_pos,
                                                 esi, edi, order, E,
                                                 m1, b1, dist_w, dist_b, hsum);
    agg_ln<<<D_NODES/64, 256, 0, stream>>>(hsum, m2, b2, deg, dst_enc, ln_g, ln_b, act);
    final_kernel<<<D_NODES/64, 256, 0, stream>>>(act, mout, out_b, dst_feat, (float*)d_out);
}

// Round 3
// 279.811 us; speedup vs baseline: 1.1440x; 1.1440x over previous
//
#include <hip/hip_runtime.h>

typedef unsigned short ushort_t;
typedef unsigned int uint_t;
typedef short bhalf8 __attribute__((ext_vector_type(8)));
typedef float f32x4 __attribute__((ext_vector_type(4)));

__device__ __forceinline__ float b2f(ushort_t u) {
    union { uint_t i; float f; } v; v.i = ((uint_t)u) << 16; return v.f;
}
__device__ __forceinline__ ushort_t f2b(float f) {
    union { float f; uint_t i; } v; v.f = f;
    uint_t r = v.i + 0x7fffu + ((v.i >> 16) & 1u);
    return (ushort_t)(r >> 16);
}

// ---------------------------------------------------------------------------
// prep kernel:
//   blocks [0,56):               weight transform fp32 -> bf16 MFMA-B order
//   blocks [56, 56+countB):      degree count (atomics)
//   blocks [56+countB, +zeroB):  zero hsum
// 7 transformed matrices, each 128x128, KS=4:
//   0:src_w 1:dst_w 2:w2 3:out_w 4:w1a(rows 0-127) 5:w1b(128-255) 6:w1c(256-383)
// out[((nt*4+ks)*64+lane)*8+j] = in[(ks*32+(lane>>4)*8+j)*128 + nt*16 + (lane&15)]
// ---------------------------------------------------------------------------
__global__ __launch_bounds__(256) void prep_kernel(
    const float* __restrict__ wsrc, const float* __restrict__ wdst,
    const float* __restrict__ w2,   const float* __restrict__ wout,
    const float* __restrict__ w1,
    ushort_t* __restrict__ msrc, ushort_t* __restrict__ mdst,
    ushort_t* __restrict__ m2,   ushort_t* __restrict__ mout,
    ushort_t* __restrict__ m1a,  ushort_t* __restrict__ m1b,
    ushort_t* __restrict__ m1c,
    const int* __restrict__ edi, int E, int* __restrict__ deg,
    float* __restrict__ hsum, int countB, int zeroB, int Dn)
{
    int b = blockIdx.x, tid = threadIdx.x;
    if (b < 56) {
        const float* ins[7] = { wsrc, wdst, w2, wout, w1, w1 + 128*128, w1 + 256*128 };
        ushort_t* outs[7]   = { msrc, mdst, m2, mout, m1a, m1b, m1c };
        int mat = b >> 3;
        const float* in = ins[mat];
        ushort_t* out = outs[mat];
        int flat = (b & 7)*256 + tid;
        int nt = flat >> 8, rem = flat & 255;
        int ks = rem >> 6, lane = rem & 63;
        int q = lane >> 4, m = lane & 15;
        #pragma unroll
        for (int j = 0; j < 8; ++j)
            out[flat*8 + j] = f2b(in[(ks*32 + q*8 + j)*128 + nt*16 + m]);
    } else if (b < 56 + countB) {
        int i = (b - 56)*256 + tid;
        if (i < E) atomicAdd(&deg[edi[i]], 1);
    } else {
        // zero hsum: Dn*128 floats over zeroB blocks
        int zb = b - 56 - countB;
        float4* h4 = (float4*)hsum;
        int total4 = Dn*32;                       // float4 count
        for (int i = zb*256 + tid; i < total4; i += zeroB*256)
            h4[i] = make_float4(0.f, 0.f, 0.f, 0.f);
    }
}

// ---------------------------------------------------------------------------
// enc2: fused  enc = relu(A@W+b)  then  C = enc@Wc   (both 128x128 GEMMs)
// blocks [0, Sb): src path -> Csrc (enc not stored)
// blocks [Sb, Sb+Db): dst path -> dst_enc (stored) and Cdst
// ---------------------------------------------------------------------------
__global__ __launch_bounds__(256) void enc2_kernel(
    const float* __restrict__ src_feat, const float* __restrict__ dst_feat,
    const ushort_t* __restrict__ msrc, const ushort_t* __restrict__ mdst,
    const ushort_t* __restrict__ m1a,  const ushort_t* __restrict__ m1c,
    const float* __restrict__ src_b,   const float* __restrict__ dst_b,
    ushort_t* __restrict__ Csrc, ushort_t* __restrict__ Cdst,
    ushort_t* __restrict__ dst_enc, int Sb)
{
    __shared__ ushort_t A_l[64*136];
    __shared__ ushort_t E_l[64*136];
    __shared__ float b_l[128];
    int tid = threadIdx.x, blk = blockIdx.x;

    const float* A; const ushort_t *W1m, *W2m; const float* bias;
    ushort_t *outC, *outEnc; int rowbase;
    if (blk < Sb) { A = src_feat; W1m = msrc; W2m = m1a; bias = src_b;
                    outC = Csrc; outEnc = nullptr; rowbase = blk*64; }
    else          { A = dst_feat; W1m = mdst; W2m = m1c; bias = dst_b;
                    outC = Cdst; outEnc = dst_enc; rowbase = (blk - Sb)*64; }

    const float4* A4 = (const float4*)A;
    for (int i = tid; i < 2048; i += 256) {          // 64 rows x 32 float4
        int r = i >> 5, c = i & 31;
        float4 v = A4[(size_t)(rowbase + r)*32 + c];
        uint2 u;
        u.x = (uint_t)f2b(v.x) | ((uint_t)f2b(v.y) << 16);
        u.y = (uint_t)f2b(v.z) | ((uint_t)f2b(v.w) << 16);
        *(uint2*)(A_l + r*136 + c*4) = u;
    }
    if (tid < 128) b_l[tid] = bias[tid];
    __syncthreads();

    int lane = tid & 63, w = tid >> 6, q = lane >> 4, m = lane & 15;
    const bhalf8* Wv1 = (const bhalf8*)W1m;
    f32x4 acc[4][2] = {};
    #pragma unroll
    for (int ks = 0; ks < 4; ++ks) {
        bhalf8 bf0 = Wv1[((2*w)*4 + ks)*64 + lane];
        bhalf8 bf1 = Wv1[((2*w+1)*4 + ks)*64 + lane];
        #pragma unroll
        for (int mt = 0; mt < 4; ++mt) {
            bhalf8 a = *(const bhalf8*)(A_l + (mt*16 + m)*136 + ks*32 + q*8);
            acc[mt][0] = __builtin_amdgcn_mfma_f32_16x16x32_bf16(a, bf0, acc[mt][0], 0, 0, 0);
            acc[mt][1] = __builtin_amdgcn_mfma_f32_16x16x32_bf16(a, bf1, acc[mt][1], 0, 0, 0);
        }
    }
    #pragma unroll
    for (int mt = 0; mt < 4; ++mt)
    #pragma unroll
    for (int nt = 0; nt < 2; ++nt)
    #pragma unroll
    for (int reg = 0; reg < 4; ++reg) {
        int col = w*32 + nt*16 + m;
        int row = mt*16 + q*4 + reg;
        ushort_t e = f2b(fmaxf(acc[mt][nt][reg] + b_l[col], 0.f));
        E_l[row*136 + col] = e;
        if (outEnc) outEnc[(size_t)(rowbase + row)*128 + col] = e;
    }
    __syncthreads();

    const bhalf8* Wv2 = (const bhalf8*)W2m;
    f32x4 acc2[4][2] = {};
    #pragma unroll
    for (int ks = 0; ks < 4; ++ks) {
        bhalf8 bf0 = Wv2[((2*w)*4 + ks)*64 + lane];
        bhalf8 bf1 = Wv2[((2*w+1)*4 + ks)*64 + lane];
        #pragma unroll
        for (int mt = 0; mt < 4; ++mt) {
            bhalf8 a = *(const bhalf8*)(E_l + (mt*16 + m)*136 + ks*32 + q*8);
            acc2[mt][0] = __builtin_amdgcn_mfma_f32_16x16x32_bf16(a, bf0, acc2[mt][0], 0, 0, 0);
            acc2[mt][1] = __builtin_amdgcn_mfma_f32_16x16x32_bf16(a, bf1, acc2[mt][1], 0, 0, 0);
        }
    }
    #pragma unroll
    for (int mt = 0; mt < 4; ++mt)
    #pragma unroll
    for (int nt = 0; nt < 2; ++nt)
    #pragma unroll
    for (int reg = 0; reg < 4; ++reg) {
        int col = w*32 + nt*16 + m;
        int row = mt*16 + q*4 + reg;
        outC[(size_t)(rowbase + row)*128 + col] = f2b(acc2[mt][nt][reg]);
    }
}

// ---------------------------------------------------------------------------
// CSR scan + fill
// ---------------------------------------------------------------------------
__global__ __launch_bounds__(256) void scan_deg(const int* __restrict__ deg,
                                                int* __restrict__ nxt, int per)
{
    __shared__ int sums[256];
    int t = threadIdx.x;
    int base = t*per;
    int s = 0;
    for (int i = 0; i < per; ++i) s += deg[base + i];
    sums[t] = s;
    __syncthreads();
    for (int off = 1; off < 256; off <<= 1) {
        int v = (t >= off) ? sums[t - off] : 0;
        __syncthreads();
        sums[t] += v;
        __syncthreads();
    }
    int run = sums[t] - s;
    for (int i = 0; i < per; ++i) { nxt[base + i] = run; run += deg[base + i]; }
}

__global__ __launch_bounds__(256) void fill_order(const int* __restrict__ edi, int E,
                                                  int* __restrict__ nxt,
                                                  int* __restrict__ order)
{
    int i = blockIdx.x*256 + threadIdx.x;
    if (i < E) {
        int p = atomicAdd(&nxt[edi[i]], 1);
        order[p] = i;
    }
}

// ---------------------------------------------------------------------------
// Edge kernel: 64 dst-sorted edges/block.
// X = relu(dpos@dist_w+db) bf16 [64][136] -> K=4 GEMM with W1b ->
// h = relu(acc + b1 + Csrc[s] + Cdst[d]) -> H f32 (aliases X) ->
// run-segmented atomic scatter into hsum.
// ---------------------------------------------------------------------------
__global__ __launch_bounds__(256, 4) void edge_kernel(
    const ushort_t* __restrict__ Csrc, const ushort_t* __restrict__ Cdst,
    const float* __restrict__ src_pos, const float* __restrict__ dst_pos,
    const int* __restrict__ esi, const int* __restrict__ edi,
    const int* __restrict__ order, int E,
    const ushort_t* __restrict__ w1bm, const float* __restrict__ eb1,
    const float* __restrict__ dist_w, const float* __restrict__ dist_b,
    float* __restrict__ hsum)
{
    __shared__ char xbuf[64*132*4];       // X bf16 [64][136] aliased with H f32 [64][132]
    __shared__ int es_l[64], ed_l[64], edv_l[64];
    __shared__ float dx_l[64], dy_l[64];
    __shared__ float b1_l[128], dw0_l[128], dw1_l[128], db_l[128];

    ushort_t* X = (ushort_t*)xbuf;
    float* H = (float*)xbuf;

    int tid = threadIdx.x, blk = blockIdx.x;

    if (tid < 64) {
        int slot = blk*64 + tid;
        if (slot < E) {
            int e = order[slot];
            int s = esi[e], d = edi[e];
            es_l[tid] = s; ed_l[tid] = d; edv_l[tid] = d;
            float2 sp = ((const float2*)src_pos)[s];
            float2 dp = ((const float2*)dst_pos)[d];
            dx_l[tid] = sp.x - dp.x;
            dy_l[tid] = sp.y - dp.y;
        } else {
            es_l[tid] = 0; ed_l[tid] = 0x7fffffff; edv_l[tid] = 0;
            dx_l[tid] = 0.f; dy_l[tid] = 0.f;
        }
    }
    if (tid < 128) {
        b1_l[tid]  = eb1[tid];
        dw0_l[tid] = dist_w[tid];
        dw1_l[tid] = dist_w[128 + tid];
        db_l[tid]  = dist_b[tid];
    }
    __syncthreads();

    // e_dist -> X (2 cols per iteration, packed uint store)
    for (int i = tid; i < 4096; i += 256) {
        int r = i >> 6, j2 = (i & 63)*2;
        float dx = dx_l[r], dy = dy_l[r];
        float v0 = fmaxf(dx*dw0_l[j2]   + dy*dw1_l[j2]   + db_l[j2],   0.f);
        float v1 = fmaxf(dx*dw0_l[j2+1] + dy*dw1_l[j2+1] + db_l[j2+1], 0.f);
        *(uint_t*)(X + r*136 + j2) = (uint_t)f2b(v0) | ((uint_t)f2b(v1) << 16);
    }
    __syncthreads();

    int lane = tid & 63, w = tid >> 6, q = lane >> 4, m = lane & 15;
    f32x4 acc[4][2] = {};
    const bhalf8* Wv = (const bhalf8*)w1bm;
    #pragma unroll
    for (int ks = 0; ks < 4; ++ks) {
        bhalf8 bf0 = Wv[((2*w)*4 + ks)*64 + lane];
        bhalf8 bf1 = Wv[((2*w+1)*4 + ks)*64 + lane];
        #pragma unroll
        for (int mt = 0; mt < 4; ++mt) {
            bhalf8 a = *(const bhalf8*)(X + (mt*16 + m)*136 + ks*32 + q*8);
            acc[mt][0] = __builtin_amdgcn_mfma_f32_16x16x32_bf16(a, bf0, acc[mt][0], 0, 0, 0);
            acc[mt][1] = __builtin_amdgcn_mfma_f32_16x16x32_bf16(a, bf1, acc[mt][1], 0, 0, 0);
        }
    }
    __syncthreads();   // all X reads done before H overwrites

    #pragma unroll
    for (int mt = 0; mt < 4; ++mt)
    #pragma unroll
    for (int reg = 0; reg < 4; ++reg) {
        int row = mt*16 + q*4 + reg;
        size_t s = (size_t)es_l[row], d = (size_t)edv_l[row];
        #pragma unroll
        for (int nt = 0; nt < 2; ++nt) {
            int col = w*32 + nt*16 + m;
            float v = acc[mt][nt][reg] + b1_l[col]
                    + b2f(Csrc[s*128 + col]) + b2f(Cdst[d*128 + col]);
            H[row*132 + col] = fmaxf(v, 0.f);
        }
    }
    __syncthreads();

    // run-segmented reduction over the dst-sorted tile, one atomic per (run, col)
    if (tid < 128) {
        int j = tid;
        float a = 0.f;
        for (int r = 0; r < 64; ++r) {
            a += H[r*132 + j];
            int dcur = ed_l[r];
            bool bnd = (r == 63) || (ed_l[r + 1] != dcur);
            if (bnd) {
                if (dcur != 0x7fffffff) atomicAdd(&hsum[(size_t)dcur*128 + j], a);
                a = 0.f;
            }
        }
    }
}

// ---------------------------------------------------------------------------
// aggfinal: agg = dst_enc + hsum@W2 + deg*b2 ; LayerNorm ; relu ->
//           out = relu(act@out_w + out_b + dst_feat)
// ---------------------------------------------------------------------------
__global__ __launch_bounds__(256) void aggfinal_kernel(
    const float* __restrict__ hsum, const ushort_t* __restrict__ w2m,
    const float* __restrict__ b2, const int* __restrict__ deg,
    const ushort_t* __restrict__ dst_enc, const float* __restrict__ ln_g,
    const float* __restrict__ ln_b, const ushort_t* __restrict__ moutm,
    const float* __restrict__ out_b, const float* __restrict__ dst_feat,
    float* __restrict__ out)
{
    __shared__ char buf[64*132*4];   // A_l bf16 [64][136] aliased with Y f32 [64][132]
    __shared__ ushort_t act_l[64*136];
    __shared__ float b2_l[128], g_l[128], bl_l[128], ob_l[128];
    __shared__ int deg_l[64];
    __shared__ float ps[64][4], ps2[64][4], mu_l[64], inv_l[64];

    ushort_t* A_l = (ushort_t*)buf;
    float* Y = (float*)buf;
    int tid = threadIdx.x, blk = blockIdx.x;

    const float4* hv = (const float4*)hsum;
    for (int i = tid; i < 1024; i += 256) {
        int r = i >> 4, c = i & 15;
        size_t base = (size_t)(blk*64 + r)*32 + c*2;
        float4 p0 = hv[base], p1 = hv[base + 1];
        uint4 u;
        u.x = (uint_t)f2b(p0.x) | ((uint_t)f2b(p0.y) << 16);
        u.y = (uint_t)f2b(p0.z) | ((uint_t)f2b(p0.w) << 16);
        u.z = (uint_t)f2b(p1.x) | ((uint_t)f2b(p1.y) << 16);
        u.w = (uint_t)f2b(p1.z) | ((uint_t)f2b(p1.w) << 16);
        *(uint4*)(A_l + r*136 + c*8) = u;
    }
    if (tid < 128) { b2_l[tid] = b2[tid]; g_l[tid] = ln_g[tid];
                     bl_l[tid] = ln_b[tid]; ob_l[tid] = out_b[tid]; }
    if (tid < 64) deg_l[tid] = deg[blk*64 + tid];
    __syncthreads();

    int lane = tid & 63, w = tid >> 6, q = lane >> 4, m = lane & 15;
    f32x4 acc[4][2] = {};
    const bhalf8* Wv = (const bhalf8*)w2m;
    #pragma unroll
    for (int ks = 0; ks < 4; ++ks) {
        bhalf8 bf0 = Wv[((2*w)*4 + ks)*64 + lane];
        bhalf8 bf1 = Wv[((2*w+1)*4 + ks)*64 + lane];
        #pragma unroll
        for (int mt = 0; mt < 4; ++mt) {
            bhalf8 a = *(const bhalf8*)(A_l + (mt*16 + m)*136 + ks*32 + q*8);
            acc[mt][0] = __builtin_amdgcn_mfma_f32_16x16x32_bf16(a, bf0, acc[mt][0], 0, 0, 0);
            acc[mt][1] = __builtin_amdgcn_mfma_f32_16x16x32_bf16(a, bf1, acc[mt][1], 0, 0, 0);
        }
    }
    __syncthreads();   // A_l reads done before Y overwrites

    #pragma unroll
    for (int mt = 0; mt < 4; ++mt)
    #pragma unroll
    for (int nt = 0; nt < 2; ++nt)
    #pragma unroll
    for (int reg = 0; reg < 4; ++reg) {
        int col = w*32 + nt*16 + m;
        int rowl = mt*16 + q*4 + reg;
        size_t grow = (size_t)blk*64 + rowl;
        float v = acc[mt][nt][reg] + (float)deg_l[rowl]*b2_l[col] + b2f(dst_enc[grow*128 + col]);
        Y[rowl*132 + col] = v;
    }
    __syncthreads();

    {
        int r = tid >> 2, t4 = tid & 3;
        float s = 0.f, s2 = 0.f;
        for (int jj = 0; jj < 32; ++jj) {
            float v = Y[r*132 + t4*32 + jj];
            s += v; s2 += v*v;
        }
        ps[r][t4] = s; ps2[r][t4] = s2;
    }
    __syncthreads();
    if (tid < 64) {
        int r = tid;
        float sum = ps[r][0] + ps[r][1] + ps[r][2] + ps[r][3];
        float sum2 = ps2[r][0] + ps2[r][1] + ps2[r][2] + ps2[r][3];
        float mu = sum / 128.f;
        float var = sum2 / 128.f - mu*mu;
        mu_l[r] = mu;
        inv_l[r] = 1.0f / sqrtf(var + 1e-5f);
    }
    __syncthreads();
    for (int i = tid; i < 4096; i += 256) {
        int r = i >> 6, j2 = (i & 63)*2;
        float v0 = fmaxf((Y[r*132 + j2]   - mu_l[r]) * inv_l[r] * g_l[j2]   + bl_l[j2],   0.f);
        float v1 = fmaxf((Y[r*132 + j2+1] - mu_l[r]) * inv_l[r] * g_l[j2+1] + bl_l[j2+1], 0.f);
        *(uint_t*)(act_l + r*136 + j2) = (uint_t)f2b(v0) | ((uint_t)f2b(v1) << 16);
    }
    __syncthreads();

    f32x4 acc2[4][2] = {};
    const bhalf8* Wo = (const bhalf8*)moutm;
    #pragma unroll
    for (int ks = 0; ks < 4; ++ks) {
        bhalf8 bf0 = Wo[((2*w)*4 + ks)*64 + lane];
        bhalf8 bf1 = Wo[((2*w+1)*4 + ks)*64 + lane];
        #pragma unroll
        for (int mt = 0; mt < 4; ++mt) {
            bhalf8 a = *(const bhalf8*)(act_l + (mt*16 + m)*136 + ks*32 + q*8);
            acc2[mt][0] = __builtin_amdgcn_mfma_f32_16x16x32_bf16(a, bf0, acc2[mt][0], 0, 0, 0);
            acc2[mt][1] = __builtin_amdgcn_mfma_f32_16x16x32_bf16(a, bf1, acc2[mt][1], 0, 0, 0);
        }
    }
    #pragma unroll
    for (int mt = 0; mt < 4; ++mt)
    #pragma unroll
    for (int nt = 0; nt < 2; ++nt)
    #pragma unroll
    for (int reg = 0; reg < 4; ++reg) {
        int col = w*32 + nt*16 + m;
        size_t row = (size_t)blk*64 + mt*16 + q*4 + reg;
        float v = acc2[mt][nt][reg] + ob_l[col] + dst_feat[row*128 + col];
        out[row*128 + col] = fmaxf(v, 0.f);
    }
}

// ---------------------------------------------------------------------------
extern "C" void kernel_launch(void* const* d_in, const int* in_sizes, int n_in,
                              void* d_out, int out_size, void* d_ws, size_t ws_size,
                              hipStream_t stream)
{
    const float* src_feat = (const float*)d_in[0];
    const float* src_pos  = (const float*)d_in[1];
    const float* dst_feat = (const float*)d_in[2];
    const float* dst_pos  = (const float*)d_in[3];
    const float* src_w    = (const float*)d_in[4];
    const float* src_b    = (const float*)d_in[5];
    const float* dst_w    = (const float*)d_in[6];
    const float* dst_b    = (const float*)d_in[7];
    const float* dist_w   = (const float*)d_in[8];
    const float* dist_b   = (const float*)d_in[9];
    const float* w1       = (const float*)d_in[10];
    const float* b1       = (const float*)d_in[11];
    const float* w2       = (const float*)d_in[12];
    const float* b2       = (const float*)d_in[13];
    const float* ln_g     = (const float*)d_in[14];
    const float* ln_b     = (const float*)d_in[15];
    const float* out_w    = (const float*)d_in[16];
    const float* out_b    = (const float*)d_in[17];
    const int* esi        = (const int*)d_in[18];
    const int* edi        = (const int*)d_in[19];
    int E = in_sizes[18];
    int S = in_sizes[0] / 128;
    int D = in_sizes[2] / 128;

    char* ws = (char*)d_ws;
    size_t off = 0;
    auto alloc = [&](size_t bytes) { char* p = ws + off; off += (bytes + 511) & ~(size_t)511; return p; };
    ushort_t* Csrc    = (ushort_t*)alloc((size_t)S*128*2);
    ushort_t* Cdst    = (ushort_t*)alloc((size_t)D*128*2);
    ushort_t* dst_enc = (ushort_t*)alloc((size_t)D*128*2);
    float*    hsum    = (float*)   alloc((size_t)D*128*4);
    ushort_t* msrc    = (ushort_t*)alloc(128*128*2);
    ushort_t* mdst    = (ushort_t*)alloc(128*128*2);
    ushort_t* m2      = (ushort_t*)alloc(128*128*2);
    ushort_t* mout    = (ushort_t*)alloc(128*128*2);
    ushort_t* m1a     = (ushort_t*)alloc(128*128*2);
    ushort_t* m1b     = (ushort_t*)alloc(128*128*2);
    ushort_t* m1c     = (ushort_t*)alloc(128*128*2);
    int*      deg     = (int*)     alloc((size_t)D*4);
    int*      nxt     = (int*)     alloc((size_t)D*4);
    int*      order   = (int*)     alloc((size_t)E*4);

    hipMemsetAsync(deg, 0, (size_t)D*4, stream);

    int countB = (E + 255)/256;
    int zeroB = 256;
    prep_kernel<<<56 + countB + zeroB, 256, 0, stream>>>(
        src_w, dst_w, w2, out_w, w1,
        msrc, mdst, m2, mout, m1a, m1b, m1c,
        edi, E, deg, hsum, countB, zeroB, D);

    int Sb = S/64, Db = D/64;
    enc2_kernel<<<Sb + Db, 256, 0, stream>>>(
        src_feat, dst_feat, msrc, mdst, m1a, m1c, src_b, dst_b,
        Csrc, Cdst, dst_enc, Sb);

    scan_deg<<<1, 256, 0, stream>>>(deg, nxt, D/256);
    fill_order<<<(E + 255)/256, 256, 0, stream>>>(edi, E, nxt, order);

    edge_kernel<<<(E + 63)/64, 256, 0, stream>>>(
        Csrc, Cdst, src_pos, dst_pos, esi, edi, order, E,
        m1b, b1, dist_w, dist_b, hsum);

    aggfinal_kernel<<<Db, 256, 0, stream>>>(
        hsum, m2, b2, deg, dst_enc, ln_g, ln_b,
        mout, out_b, dst_feat, (float*)d_out);
}

// Round 4
// 247.482 us; speedup vs baseline: 1.2934x; 1.1306x over previous
//
#include <hip/hip_runtime.h>

typedef unsigned short ushort_t;
typedef unsigned int uint_t;
typedef short bhalf8 __attribute__((ext_vector_type(8)));
typedef float f32x4 __attribute__((ext_vector_type(4)));

__device__ __forceinline__ float b2f(ushort_t u) {
    union { uint_t i; float f; } v; v.i = ((uint_t)u) << 16; return v.f;
}
__device__ __forceinline__ ushort_t f2b(float f) {
    union { float f; uint_t i; } v; v.f = f;
    uint_t r = v.i + 0x7fffu + ((v.i >> 16) & 1u);
    return (ushort_t)(r >> 16);
}
// packed bf16x2 add with truncation (cheap; |err| ~0.4% used only for G whose |val|~0.05)
__device__ __forceinline__ uint_t addpack_trunc(uint_t a, uint_t b) {
    union { uint_t i; float f; } t0, t1, s0, s1;
    t0.i = a << 16;          s0.i = b << 16;
    t1.i = a & 0xffff0000u;  s1.i = b & 0xffff0000u;
    float lo = t0.f + s0.f, hi = t1.f + s1.f;
    union { float f; uint_t i; } rl, rh; rl.f = lo; rh.f = hi;
    return (rl.i >> 16) | (rh.i & 0xffff0000u);
}

// ---------------------------------------------------------------------------
// prep kernel: [0,56) weight transform; [56,56+countB) degree count;
// rest: zero hsum.  7 matrices 128x128, KS=4:
//   0:src_w 1:dst_w 2:w2 3:out_w 4:w1a 5:w1b 6:w1c
// ---------------------------------------------------------------------------
__global__ __launch_bounds__(256) void prep_kernel(
    const float* __restrict__ wsrc, const float* __restrict__ wdst,
    const float* __restrict__ w2,   const float* __restrict__ wout,
    const float* __restrict__ w1,
    ushort_t* __restrict__ msrc, ushort_t* __restrict__ mdst,
    ushort_t* __restrict__ m2,   ushort_t* __restrict__ mout,
    ushort_t* __restrict__ m1a,  ushort_t* __restrict__ m1b,
    ushort_t* __restrict__ m1c,
    const int* __restrict__ edi, int E, int* __restrict__ deg,
    float* __restrict__ hsum, int countB, int zeroB, int Dn)
{
    int b = blockIdx.x, tid = threadIdx.x;
    if (b < 56) {
        const float* ins[7] = { wsrc, wdst, w2, wout, w1, w1 + 128*128, w1 + 256*128 };
        ushort_t* outs[7]   = { msrc, mdst, m2, mout, m1a, m1b, m1c };
        int mat = b >> 3;
        const float* in = ins[mat];
        ushort_t* out = outs[mat];
        int flat = (b & 7)*256 + tid;
        int nt = flat >> 8, rem = flat & 255;
        int ks = rem >> 6, lane = rem & 63;
        int q = lane >> 4, m = lane & 15;
        #pragma unroll
        for (int j = 0; j < 8; ++j)
            out[flat*8 + j] = f2b(in[(ks*32 + q*8 + j)*128 + nt*16 + m]);
    } else if (b < 56 + countB) {
        int i = (b - 56)*256 + tid;
        if (i < E) atomicAdd(&deg[edi[i]], 1);
    } else {
        int zb = b - 56 - countB;
        float4* h4 = (float4*)hsum;
        int total4 = Dn*32;
        for (int i = zb*256 + tid; i < total4; i += zeroB*256)
            h4[i] = make_float4(0.f, 0.f, 0.f, 0.f);
    }
}

// ---------------------------------------------------------------------------
// enc2: enc = relu(A@W+b) then C = enc@Wc (two chained 128x128 GEMMs)
// ---------------------------------------------------------------------------
__global__ __launch_bounds__(256) void enc2_kernel(
    const float* __restrict__ src_feat, const float* __restrict__ dst_feat,
    const ushort_t* __restrict__ msrc, const ushort_t* __restrict__ mdst,
    const ushort_t* __restrict__ m1a,  const ushort_t* __restrict__ m1c,
    const float* __restrict__ src_b,   const float* __restrict__ dst_b,
    ushort_t* __restrict__ Csrc, ushort_t* __restrict__ Cdst,
    ushort_t* __restrict__ dst_enc, int Sb)
{
    __shared__ ushort_t A_l[64*136];
    __shared__ ushort_t E_l[64*136];
    __shared__ float b_l[128];
    int tid = threadIdx.x, blk = blockIdx.x;

    const float* A; const ushort_t *W1m, *W2m; const float* bias;
    ushort_t *outC, *outEnc; int rowbase;
    if (blk < Sb) { A = src_feat; W1m = msrc; W2m = m1a; bias = src_b;
                    outC = Csrc; outEnc = nullptr; rowbase = blk*64; }
    else          { A = dst_feat; W1m = mdst; W2m = m1c; bias = dst_b;
                    outC = Cdst; outEnc = dst_enc; rowbase = (blk - Sb)*64; }

    const float4* A4 = (const float4*)A;
    for (int i = tid; i < 2048; i += 256) {
        int r = i >> 5, c = i & 31;
        float4 v = A4[(size_t)(rowbase + r)*32 + c];
        uint2 u;
        u.x = (uint_t)f2b(v.x) | ((uint_t)f2b(v.y) << 16);
        u.y = (uint_t)f2b(v.z) | ((uint_t)f2b(v.w) << 16);
        *(uint2*)(A_l + r*136 + c*4) = u;
    }
    if (tid < 128) b_l[tid] = bias[tid];
    __syncthreads();

    int lane = tid & 63, w = tid >> 6, q = lane >> 4, m = lane & 15;
    const bhalf8* Wv1 = (const bhalf8*)W1m;
    f32x4 acc[4][2] = {};
    #pragma unroll
    for (int ks = 0; ks < 4; ++ks) {
        bhalf8 bf0 = Wv1[((2*w)*4 + ks)*64 + lane];
        bhalf8 bf1 = Wv1[((2*w+1)*4 + ks)*64 + lane];
        #pragma unroll
        for (int mt = 0; mt < 4; ++mt) {
            bhalf8 a = *(const bhalf8*)(A_l + (mt*16 + m)*136 + ks*32 + q*8);
            acc[mt][0] = __builtin_amdgcn_mfma_f32_16x16x32_bf16(a, bf0, acc[mt][0], 0, 0, 0);
            acc[mt][1] = __builtin_amdgcn_mfma_f32_16x16x32_bf16(a, bf1, acc[mt][1], 0, 0, 0);
        }
    }
    #pragma unroll
    for (int mt = 0; mt < 4; ++mt)
    #pragma unroll
    for (int nt = 0; nt < 2; ++nt)
    #pragma unroll
    for (int reg = 0; reg < 4; ++reg) {
        int col = w*32 + nt*16 + m;
        int row = mt*16 + q*4 + reg;
        ushort_t e = f2b(fmaxf(acc[mt][nt][reg] + b_l[col], 0.f));
        E_l[row*136 + col] = e;
        if (outEnc) outEnc[(size_t)(rowbase + row)*128 + col] = e;
    }
    __syncthreads();

    const bhalf8* Wv2 = (const bhalf8*)W2m;
    f32x4 acc2[4][2] = {};
    #pragma unroll
    for (int ks = 0; ks < 4; ++ks) {
        bhalf8 bf0 = Wv2[((2*w)*4 + ks)*64 + lane];
        bhalf8 bf1 = Wv2[((2*w+1)*4 + ks)*64 + lane];
        #pragma unroll
        for (int mt = 0; mt < 4; ++mt) {
            bhalf8 a = *(const bhalf8*)(E_l + (mt*16 + m)*136 + ks*32 + q*8);
            acc2[mt][0] = __builtin_amdgcn_mfma_f32_16x16x32_bf16(a, bf0, acc2[mt][0], 0, 0, 0);
            acc2[mt][1] = __builtin_amdgcn_mfma_f32_16x16x32_bf16(a, bf1, acc2[mt][1], 0, 0, 0);
        }
    }
    #pragma unroll
    for (int mt = 0; mt < 4; ++mt)
    #pragma unroll
    for (int nt = 0; nt < 2; ++nt)
    #pragma unroll
    for (int reg = 0; reg < 4; ++reg) {
        int col = w*32 + nt*16 + m;
        int row = mt*16 + q*4 + reg;
        outC[(size_t)(rowbase + row)*128 + col] = f2b(acc2[mt][nt][reg]);
    }
}

// ---------------------------------------------------------------------------
// CSR scan (1024 threads, int4 loads) + fill into sorted_s/sorted_d
// ---------------------------------------------------------------------------
__global__ __launch_bounds__(1024) void scan_deg(const int* __restrict__ deg,
                                                 int* __restrict__ nxt, int Dn)
{
    __shared__ int sums[1024];
    int t = threadIdx.x;
    int per = Dn >> 10;                       // 16 for D=16384
    const int4* d4 = (const int4*)(deg + t*per);
    int4 v[4]; int s = 0;
    #pragma unroll
    for (int k = 0; k < 4; ++k) { v[k] = d4[k]; s += v[k].x + v[k].y + v[k].z + v[k].w; }
    sums[t] = s;
    __syncthreads();
    for (int off = 1; off < 1024; off <<= 1) {
        int x = (t >= off) ? sums[t - off] : 0;
        __syncthreads();
        sums[t] += x;
        __syncthreads();
    }
    int run = sums[t] - s;
    int4* n4 = (int4*)(nxt + t*per);
    #pragma unroll
    for (int k = 0; k < 4; ++k) {
        int4 o;
        o.x = run; run += v[k].x;
        o.y = run; run += v[k].y;
        o.z = run; run += v[k].z;
        o.w = run; run += v[k].w;
        n4[k] = o;
    }
}

__global__ __launch_bounds__(256) void fill_sorted(
    const int* __restrict__ esi, const int* __restrict__ edi, int E,
    int* __restrict__ nxt, int* __restrict__ ss, int* __restrict__ sd)
{
    int i = blockIdx.x*256 + threadIdx.x;
    if (i < E) {
        int s = esi[i], d = edi[i];
        int p = atomicAdd(&nxt[d], 1);
        ss[p] = s; sd[p] = d;
    }
}

// ---------------------------------------------------------------------------
// Edge kernel: 64 dst-sorted edges/block.
// Staging: G = Csrc[s]+Cdst[d] (vectorized uint4 gather -> bf16 LDS),
//          X = relu(dpos@dist_w+db) bf16 LDS.
// K=4 GEMM with W1b -> h = relu(acc + b1 + G) -> H bf16 (in-place over X) ->
// segmented reduction (256 threads: col x half) -> atomicAdd hsum.
// ---------------------------------------------------------------------------
__global__ __launch_bounds__(256, 4) void edge_kernel(
    const ushort_t* __restrict__ Csrc, const ushort_t* __restrict__ Cdst,
    const float* __restrict__ src_pos, const float* __restrict__ dst_pos,
    const int* __restrict__ sorted_s, const int* __restrict__ sorted_d, int E,
    const ushort_t* __restrict__ w1bm, const float* __restrict__ eb1,
    const float* __restrict__ dist_w, const float* __restrict__ dist_b,
    float* __restrict__ hsum)
{
    __shared__ ushort_t X[64*136];      // dist bf16; later H bf16 (in-place)
    __shared__ ushort_t G_l[64*136];    // Csrc[s]+Cdst[d] bf16
    __shared__ int s_l[64], ed_l[64], dv_l[64];
    __shared__ float dx_l[64], dy_l[64];
    __shared__ float b1_l[128], dw0_l[128], dw1_l[128], db_l[128];

    int tid = threadIdx.x, blk = blockIdx.x;

    if (tid < 64) {
        int slot = blk*64 + tid;
        if (slot < E) {
            int s = sorted_s[slot], d = sorted_d[slot];
            s_l[tid] = s; ed_l[tid] = d; dv_l[tid] = d;
            float2 sp = ((const float2*)src_pos)[s];
            float2 dp = ((const float2*)dst_pos)[d];
            dx_l[tid] = sp.x - dp.x;
            dy_l[tid] = sp.y - dp.y;
        } else {
            s_l[tid] = 0; ed_l[tid] = 0x7fffffff; dv_l[tid] = 0;
            dx_l[tid] = 0.f; dy_l[tid] = 0.f;
        }
    }
    if (tid < 128) {
        b1_l[tid]  = eb1[tid];
        dw0_l[tid] = dist_w[tid];
        dw1_l[tid] = dist_w[128 + tid];
        db_l[tid]  = dist_b[tid];
    }
    __syncthreads();

    // G gather: coalesced uint4 (8 bf16) per lane, 4 iterations/thread
    const uint4* cs4 = (const uint4*)Csrc;
    const uint4* cd4 = (const uint4*)Cdst;
    for (int i = tid; i < 1024; i += 256) {
        int r = i >> 4, c = i & 15;
        uint4 a = cs4[(size_t)s_l[r]*16 + c];
        uint4 b = cd4[(size_t)dv_l[r]*16 + c];
        uint4 u;
        u.x = addpack_trunc(a.x, b.x);
        u.y = addpack_trunc(a.y, b.y);
        u.z = addpack_trunc(a.z, b.z);
        u.w = addpack_trunc(a.w, b.w);
        *(uint4*)(G_l + r*136 + c*8) = u;
    }
    // dist features -> X
    for (int i = tid; i < 4096; i += 256) {
        int r = i >> 6, j2 = (i & 63)*2;
        float dx = dx_l[r], dy = dy_l[r];
        float v0 = fmaxf(dx*dw0_l[j2]   + dy*dw1_l[j2]   + db_l[j2],   0.f);
        float v1 = fmaxf(dx*dw0_l[j2+1] + dy*dw1_l[j2+1] + db_l[j2+1], 0.f);
        *(uint_t*)(X + r*136 + j2) = (uint_t)f2b(v0) | ((uint_t)f2b(v1) << 16);
    }
    __syncthreads();

    int lane = tid & 63, w = tid >> 6, q = lane >> 4, m = lane & 15;
    f32x4 acc[4][2] = {};
    const bhalf8* Wv = (const bhalf8*)w1bm;
    #pragma unroll
    for (int ks = 0; ks < 4; ++ks) {
        bhalf8 bf0 = Wv[((2*w)*4 + ks)*64 + lane];
        bhalf8 bf1 = Wv[((2*w+1)*4 + ks)*64 + lane];
        #pragma unroll
        for (int mt = 0; mt < 4; ++mt) {
            bhalf8 a = *(const bhalf8*)(X + (mt*16 + m)*136 + ks*32 + q*8);
            acc[mt][0] = __builtin_amdgcn_mfma_f32_16x16x32_bf16(a, bf0, acc[mt][0], 0, 0, 0);
            acc[mt][1] = __builtin_amdgcn_mfma_f32_16x16x32_bf16(a, bf1, acc[mt][1], 0, 0, 0);
        }
    }
    __syncthreads();   // all X reads done before H overwrites in place

    #pragma unroll
    for (int mt = 0; mt < 4; ++mt)
    #pragma unroll
    for (int reg = 0; reg < 4; ++reg) {
        int row = mt*16 + q*4 + reg;
        #pragma unroll
        for (int nt = 0; nt < 2; ++nt) {
            int col = w*32 + nt*16 + m;
            float v = acc[mt][nt][reg] + b1_l[col] + b2f(G_l[row*136 + col]);
            X[row*136 + col] = f2b(fmaxf(v, 0.f));
        }
    }
    __syncthreads();

    // segmented reduction: 256 threads = 128 cols x 2 halves of 32 rows each;
    // boundary predicate is wave-uniform (same r across lanes)
    {
        int j = tid & 127, h = tid >> 7;
        int rend = h*32 + 32;
        float a = 0.f;
        for (int r = h*32; r < rend; ++r) {
            a += b2f(X[r*136 + j]);
            int dcur = ed_l[r];
            bool bnd = (r == rend - 1) || (ed_l[r + 1] != dcur);
            if (bnd) {
                if (dcur != 0x7fffffff) atomicAdd(&hsum[(size_t)dcur*128 + j], a);
                a = 0.f;
            }
        }
    }
}

// ---------------------------------------------------------------------------
// aggfinal: agg = dst_enc + hsum@W2 + deg*b2 ; LayerNorm ; relu ->
//           out = relu(act@out_w + out_b + dst_feat)
// ---------------------------------------------------------------------------
__global__ __launch_bounds__(256) void aggfinal_kernel(
    const float* __restrict__ hsum, const ushort_t* __restrict__ w2m,
    const float* __restrict__ b2, const int* __restrict__ deg,
    const ushort_t* __restrict__ dst_enc, const float* __restrict__ ln_g,
    const float* __restrict__ ln_b, const ushort_t* __restrict__ moutm,
    const float* __restrict__ out_b, const float* __restrict__ dst_feat,
    float* __restrict__ out)
{
    __shared__ char buf[64*132*4];   // A_l bf16 [64][136] aliased with Y f32 [64][132]
    __shared__ ushort_t act_l[64*136];
    __shared__ float b2_l[128], g_l[128], bl_l[128], ob_l[128];
    __shared__ int deg_l[64];
    __shared__ float ps[64][4], ps2[64][4], mu_l[64], inv_l[64];

    ushort_t* A_l = (ushort_t*)buf;
    float* Y = (float*)buf;
    int tid = threadIdx.x, blk = blockIdx.x;

    const float4* hv = (const float4*)hsum;
    for (int i = tid; i < 1024; i += 256) {
        int r = i >> 4, c = i & 15;
        size_t base = (size_t)(blk*64 + r)*32 + c*2;
        float4 p0 = hv[base], p1 = hv[base + 1];
        uint4 u;
        u.x = (uint_t)f2b(p0.x) | ((uint_t)f2b(p0.y) << 16);
        u.y = (uint_t)f2b(p0.z) | ((uint_t)f2b(p0.w) << 16);
        u.z = (uint_t)f2b(p1.x) | ((uint_t)f2b(p1.y) << 16);
        u.w = (uint_t)f2b(p1.z) | ((uint_t)f2b(p1.w) << 16);
        *(uint4*)(A_l + r*136 + c*8) = u;
    }
    if (tid < 128) { b2_l[tid] = b2[tid]; g_l[tid] = ln_g[tid];
                     bl_l[tid] = ln_b[tid]; ob_l[tid] = out_b[tid]; }
    if (tid < 64) deg_l[tid] = deg[blk*64 + tid];
    __syncthreads();

    int lane = tid & 63, w = tid >> 6, q = lane >> 4, m = lane & 15;
    f32x4 acc[4][2] = {};
    const bhalf8* Wv = (const bhalf8*)w2m;
    #pragma unroll
    for (int ks = 0; ks < 4; ++ks) {
        bhalf8 bf0 = Wv[((2*w)*4 + ks)*64 + lane];
        bhalf8 bf1 = Wv[((2*w+1)*4 + ks)*64 + lane];
        #pragma unroll
        for (int mt = 0; mt < 4; ++mt) {
            bhalf8 a = *(const bhalf8*)(A_l + (mt*16 + m)*136 + ks*32 + q*8);
            acc[mt][0] = __builtin_amdgcn_mfma_f32_16x16x32_bf16(a, bf0, acc[mt][0], 0, 0, 0);
            acc[mt][1] = __builtin_amdgcn_mfma_f32_16x16x32_bf16(a, bf1, acc[mt][1], 0, 0, 0);
        }
    }
    __syncthreads();   // A_l reads done before Y overwrites

    #pragma unroll
    for (int mt = 0; mt < 4; ++mt)
    #pragma unroll
    for (int nt = 0; nt < 2; ++nt)
    #pragma unroll
    for (int reg = 0; reg < 4; ++reg) {
        int col = w*32 + nt*16 + m;
        int rowl = mt*16 + q*4 + reg;
        size_t grow = (size_t)blk*64 + rowl;
        float v = acc[mt][nt][reg] + (float)deg_l[rowl]*b2_l[col] + b2f(dst_enc[grow*128 + col]);
        Y[rowl*132 + col] = v;
    }
    __syncthreads();

    {
        int r = tid >> 2, t4 = tid & 3;
        float s = 0.f, s2 = 0.f;
        for (int jj = 0; jj < 32; ++jj) {
            float v = Y[r*132 + t4*32 + jj];
            s += v; s2 += v*v;
        }
        ps[r][t4] = s; ps2[r][t4] = s2;
    }
    __syncthreads();
    if (tid < 64) {
        int r = tid;
        float sum = ps[r][0] + ps[r][1] + ps[r][2] + ps[r][3];
        float sum2 = ps2[r][0] + ps2[r][1] + ps2[r][2] + ps2[r][3];
        float mu = sum / 128.f;
        float var = sum2 / 128.f - mu*mu;
        mu_l[r] = mu;
        inv_l[r] = 1.0f / sqrtf(var + 1e-5f);
    }
    __syncthreads();
    for (int i = tid; i < 4096; i += 256) {
        int r = i >> 6, j2 = (i & 63)*2;
        float v0 = fmaxf((Y[r*132 + j2]   - mu_l[r]) * inv_l[r] * g_l[j2]   + bl_l[j2],   0.f);
        float v1 = fmaxf((Y[r*132 + j2+1] - mu_l[r]) * inv_l[r] * g_l[j2+1] + bl_l[j2+1], 0.f);
        *(uint_t*)(act_l + r*136 + j2) = (uint_t)f2b(v0) | ((uint_t)f2b(v1) << 16);
    }
    __syncthreads();

    f32x4 acc2[4][2] = {};
    const bhalf8* Wo = (const bhalf8*)moutm;
    #pragma unroll
    for (int ks = 0; ks < 4; ++ks) {
        bhalf8 bf0 = Wo[((2*w)*4 + ks)*64 + lane];
        bhalf8 bf1 = Wo[((2*w+1)*4 + ks)*64 + lane];
        #pragma unroll
        for (int mt = 0; mt < 4; ++mt) {
            bhalf8 a = *(const bhalf8*)(act_l + (mt*16 + m)*136 + ks*32 + q*8);
            acc2[mt][0] = __builtin_amdgcn_mfma_f32_16x16x32_bf16(a, bf0, acc2[mt][0], 0, 0, 0);
            acc2[mt][1] = __builtin_amdgcn_mfma_f32_16x16x32_bf16(a, bf1, acc2[mt][1], 0, 0, 0);
        }
    }
    #pragma unroll
    for (int mt = 0; mt < 4; ++mt)
    #pragma unroll
    for (int nt = 0; nt < 2; ++nt)
    #pragma unroll
    for (int reg = 0; reg < 4; ++reg) {
        int col = w*32 + nt*16 + m;
        size_t row = (size_t)blk*64 + mt*16 + q*4 + reg;
        float v = acc2[mt][nt][reg] + ob_l[col] + dst_feat[row*128 + col];
        out[row*128 + col] = fmaxf(v, 0.f);
    }
}

// ---------------------------------------------------------------------------
extern "C" void kernel_launch(void* const* d_in, const int* in_sizes, int n_in,
                              void* d_out, int out_size, void* d_ws, size_t ws_size,
                              hipStream_t stream)
{
    const float* src_feat = (const float*)d_in[0];
    const float* src_pos  = (const float*)d_in[1];
    const float* dst_feat = (const float*)d_in[2];
    const float* dst_pos  = (const float*)d_in[3];
    const float* src_w    = (const float*)d_in[4];
    const float* src_b    = (const float*)d_in[5];
    const float* dst_w    = (const float*)d_in[6];
    const float* dst_b    = (const float*)d_in[7];
    const float* dist_w   = (const float*)d_in[8];
    const float* dist_b   = (const float*)d_in[9];
    const float* w1       = (const float*)d_in[10];
    const float* b1       = (const float*)d_in[11];
    const float* w2       = (const float*)d_in[12];
    const float* b2       = (const float*)d_in[13];
    const float* ln_g     = (const float*)d_in[14];
    const float* ln_b     = (const float*)d_in[15];
    const float* out_w    = (const float*)d_in[16];
    const float* out_b    = (const float*)d_in[17];
    const int* esi        = (const int*)d_in[18];
    const int* edi        = (const int*)d_in[19];
    int E = in_sizes[18];
    int S = in_sizes[0] / 128;
    int D = in_sizes[2] / 128;

    char* ws = (char*)d_ws;
    size_t off = 0;
    auto alloc = [&](size_t bytes) { char* p = ws + off; off += (bytes + 511) & ~(size_t)511; return p; };
    ushort_t* Csrc    = (ushort_t*)alloc((size_t)S*128*2);
    ushort_t* Cdst    = (ushort_t*)alloc((size_t)D*128*2);
    ushort_t* dst_enc = (ushort_t*)alloc((size_t)D*128*2);
    float*    hsum    = (float*)   alloc((size_t)D*128*4);
    ushort_t* msrc    = (ushort_t*)alloc(128*128*2);
    ushort_t* mdst    = (ushort_t*)alloc(128*128*2);
    ushort_t* m2      = (ushort_t*)alloc(128*128*2);
    ushort_t* mout    = (ushort_t*)alloc(128*128*2);
    ushort_t* m1a     = (ushort_t*)alloc(128*128*2);
    ushort_t* m1b     = (ushort_t*)alloc(128*128*2);
    ushort_t* m1c     = (ushort_t*)alloc(128*128*2);
    int*      deg     = (int*)     alloc((size_t)D*4);
    int*      nxt     = (int*)     alloc((size_t)D*4);
    int*      ss      = (int*)     alloc((size_t)E*4);
    int*      sd      = (int*)     alloc((size_t)E*4);

    hipMemsetAsync(deg, 0, (size_t)D*4, stream);

    int countB = (E + 255)/256;
    int zeroB = 256;
    prep_kernel<<<56 + countB + zeroB, 256, 0, stream>>>(
        src_w, dst_w, w2, out_w, w1,
        msrc, mdst, m2, mout, m1a, m1b, m1c,
        edi, E, deg, hsum, countB, zeroB, D);

    int Sb = S/64, Db = D/64;
    enc2_kernel<<<Sb + Db, 256, 0, stream>>>(
        src_feat, dst_feat, msrc, mdst, m1a, m1c, src_b, dst_b,
        Csrc, Cdst, dst_enc, Sb);

    scan_deg<<<1, 1024, 0, stream>>>(deg, nxt, D);
    fill_sorted<<<(E + 255)/256, 256, 0, stream>>>(esi, edi, E, nxt, ss, sd);

    edge_kernel<<<(E + 63)/64, 256, 0, stream>>>(
        Csrc, Cdst, src_pos, dst_pos, ss, sd, E,
        m1b, b1, dist_w, dist_b, hsum);

    aggfinal_kernel<<<Db, 256, 0, stream>>>(
        hsum, m2, b2, deg, dst_enc, ln_g, ln_b,
        mout, out_b, dst_feat, (float*)d_out);
}

// Round 5
// 234.228 us; speedup vs baseline: 1.3666x; 1.0566x over previous
//
#include <hip/hip_runtime.h>

typedef unsigned short ushort_t;
typedef unsigned int uint_t;
typedef short bhalf8 __attribute__((ext_vector_type(8)));
typedef float f32x4 __attribute__((ext_vector_type(4)));

__device__ __forceinline__ float b2f(ushort_t u) {
    union { uint_t i; float f; } v; v.i = ((uint_t)u) << 16; return v.f;
}
__device__ __forceinline__ ushort_t f2b(float f) {
    union { float f; uint_t i; } v; v.f = f;
    uint_t r = v.i + 0x7fffu + ((v.i >> 16) & 1u);
    return (ushort_t)(r >> 16);
}
__device__ __forceinline__ uint_t f2u(float f) {
    union { float f; uint_t i; } v; v.f = f; return v.i;
}
// pack two f32 -> bf16x2 with truncation (2 ops; used where downstream scale ~0.02)
__device__ __forceinline__ uint_t pack_trunc(float lo, float hi) {
    return (f2u(lo) >> 16) | (f2u(hi) & 0xffff0000u);
}
// packed bf16x2 add with truncation
__device__ __forceinline__ uint_t addpack_trunc(uint_t a, uint_t b) {
    union { uint_t i; float f; } t0, t1, s0, s1;
    t0.i = a << 16;          s0.i = b << 16;
    t1.i = a & 0xffff0000u;  s1.i = b & 0xffff0000u;
    return pack_trunc(t0.f + s0.f, t1.f + s1.f);
}

// ---------------------------------------------------------------------------
// prep kernel: [0,56) weight transform; [56,56+countB) degree count;
// rest: zero hsum.  7 matrices 128x128, KS=4:
//   0:src_w 1:dst_w 2:w2 3:out_w 4:w1a 5:w1b 6:w1c
// ---------------------------------------------------------------------------
__global__ __launch_bounds__(256) void prep_kernel(
    const float* __restrict__ wsrc, const float* __restrict__ wdst,
    const float* __restrict__ w2,   const float* __restrict__ wout,
    const float* __restrict__ w1,
    ushort_t* __restrict__ msrc, ushort_t* __restrict__ mdst,
    ushort_t* __restrict__ m2,   ushort_t* __restrict__ mout,
    ushort_t* __restrict__ m1a,  ushort_t* __restrict__ m1b,
    ushort_t* __restrict__ m1c,
    const int* __restrict__ edi, int E, int* __restrict__ deg,
    float* __restrict__ hsum, int countB, int zeroB, int Dn)
{
    int b = blockIdx.x, tid = threadIdx.x;
    if (b < 56) {
        const float* ins[7] = { wsrc, wdst, w2, wout, w1, w1 + 128*128, w1 + 256*128 };
        ushort_t* outs[7]   = { msrc, mdst, m2, mout, m1a, m1b, m1c };
        int mat = b >> 3;
        const float* in = ins[mat];
        ushort_t* out = outs[mat];
        int flat = (b & 7)*256 + tid;
        int nt = flat >> 8, rem = flat & 255;
        int ks = rem >> 6, lane = rem & 63;
        int q = lane >> 4, m = lane & 15;
        #pragma unroll
        for (int j = 0; j < 8; ++j)
            out[flat*8 + j] = f2b(in[(ks*32 + q*8 + j)*128 + nt*16 + m]);
    } else if (b < 56 + countB) {
        int i = (b - 56)*256 + tid;
        if (i < E) atomicAdd(&deg[edi[i]], 1);
    } else {
        int zb = b - 56 - countB;
        float4* h4 = (float4*)hsum;
        int total4 = Dn*32;
        for (int i = zb*256 + tid; i < total4; i += zeroB*256)
            h4[i] = make_float4(0.f, 0.f, 0.f, 0.f);
    }
}

// ---------------------------------------------------------------------------
// enc2: enc = relu(A@W+b) then C = enc@Wc (+ b1 on dst path)
// block Sb+Db additionally runs the degree scan (hidden under the GEMM blocks)
// ---------------------------------------------------------------------------
__global__ __launch_bounds__(256) void enc2_kernel(
    const float* __restrict__ src_feat, const float* __restrict__ dst_feat,
    const ushort_t* __restrict__ msrc, const ushort_t* __restrict__ mdst,
    const ushort_t* __restrict__ m1a,  const ushort_t* __restrict__ m1c,
    const float* __restrict__ src_b,   const float* __restrict__ dst_b,
    const float* __restrict__ b1,
    ushort_t* __restrict__ Csrc, ushort_t* __restrict__ Cdst,
    ushort_t* __restrict__ dst_enc,
    const int* __restrict__ deg, int* __restrict__ nxt, int Dn,
    int Sb, int Db)
{
    int tid = threadIdx.x, blk = blockIdx.x;

    if (blk == Sb + Db) {                       // ---- scan block ----
        __shared__ int sums[256];
        int per = Dn >> 8;                      // 64 for D=16384
        const int4* d4 = (const int4*)(deg + tid*per);
        int4 v[16]; int s = 0;
        #pragma unroll
        for (int k = 0; k < 16; ++k) { v[k] = d4[k]; s += v[k].x + v[k].y + v[k].z + v[k].w; }
        sums[tid] = s;
        __syncthreads();
        for (int off = 1; off < 256; off <<= 1) {
            int x = (tid >= off) ? sums[tid - off] : 0;
            __syncthreads();
            sums[tid] += x;
            __syncthreads();
        }
        int run = sums[tid] - s;
        int4* n4 = (int4*)(nxt + tid*per);
        #pragma unroll
        for (int k = 0; k < 16; ++k) {
            int4 o;
            o.x = run; run += v[k].x;
            o.y = run; run += v[k].y;
            o.z = run; run += v[k].z;
            o.w = run; run += v[k].w;
            n4[k] = o;
        }
        return;
    }

    __shared__ ushort_t A_l[64*136];
    __shared__ ushort_t E_l[64*136];
    __shared__ float b_l[128];
    __shared__ float b2_l[128];

    const float* A; const ushort_t *W1m, *W2m; const float* bias;
    ushort_t *outC, *outEnc; int rowbase; const float* bias2;
    if (blk < Sb) { A = src_feat; W1m = msrc; W2m = m1a; bias = src_b;
                    outC = Csrc; outEnc = nullptr; rowbase = blk*64; bias2 = nullptr; }
    else          { A = dst_feat; W1m = mdst; W2m = m1c; bias = dst_b;
                    outC = Cdst; outEnc = dst_enc; rowbase = (blk - Sb)*64; bias2 = b1; }

    const float4* A4 = (const float4*)A;
    for (int i = tid; i < 2048; i += 256) {
        int r = i >> 5, c = i & 31;
        float4 v = A4[(size_t)(rowbase + r)*32 + c];
        uint2 u;
        u.x = (uint_t)f2b(v.x) | ((uint_t)f2b(v.y) << 16);
        u.y = (uint_t)f2b(v.z) | ((uint_t)f2b(v.w) << 16);
        *(uint2*)(A_l + r*136 + c*4) = u;
    }
    if (tid < 128) { b_l[tid] = bias[tid]; b2_l[tid] = bias2 ? bias2[tid] : 0.f; }
    __syncthreads();

    int lane = tid & 63, w = tid >> 6, q = lane >> 4, m = lane & 15;
    const bhalf8* Wv1 = (const bhalf8*)W1m;
    f32x4 acc[4][2] = {};
    #pragma unroll
    for (int ks = 0; ks < 4; ++ks) {
        bhalf8 bf0 = Wv1[((2*w)*4 + ks)*64 + lane];
        bhalf8 bf1 = Wv1[((2*w+1)*4 + ks)*64 + lane];
        #pragma unroll
        for (int mt = 0; mt < 4; ++mt) {
            bhalf8 a = *(const bhalf8*)(A_l + (mt*16 + m)*136 + ks*32 + q*8);
            acc[mt][0] = __builtin_amdgcn_mfma_f32_16x16x32_bf16(a, bf0, acc[mt][0], 0, 0, 0);
            acc[mt][1] = __builtin_amdgcn_mfma_f32_16x16x32_bf16(a, bf1, acc[mt][1], 0, 0, 0);
        }
    }
    #pragma unroll
    for (int mt = 0; mt < 4; ++mt)
    #pragma unroll
    for (int nt = 0; nt < 2; ++nt)
    #pragma unroll
    for (int reg = 0; reg < 4; ++reg) {
        int col = w*32 + nt*16 + m;
        int row = mt*16 + q*4 + reg;
        ushort_t e = f2b(fmaxf(acc[mt][nt][reg] + b_l[col], 0.f));
        E_l[row*136 + col] = e;
        if (outEnc) outEnc[(size_t)(rowbase + row)*128 + col] = e;
    }
    __syncthreads();

    const bhalf8* Wv2 = (const bhalf8*)W2m;
    f32x4 acc2[4][2] = {};
    #pragma unroll
    for (int ks = 0; ks < 4; ++ks) {
        bhalf8 bf0 = Wv2[((2*w)*4 + ks)*64 + lane];
        bhalf8 bf1 = Wv2[((2*w+1)*4 + ks)*64 + lane];
        #pragma unroll
        for (int mt = 0; mt < 4; ++mt) {
            bhalf8 a = *(const bhalf8*)(E_l + (mt*16 + m)*136 + ks*32 + q*8);
            acc2[mt][0] = __builtin_amdgcn_mfma_f32_16x16x32_bf16(a, bf0, acc2[mt][0], 0, 0, 0);
            acc2[mt][1] = __builtin_amdgcn_mfma_f32_16x16x32_bf16(a, bf1, acc2[mt][1], 0, 0, 0);
        }
    }
    #pragma unroll
    for (int mt = 0; mt < 4; ++mt)
    #pragma unroll
    for (int nt = 0; nt < 2; ++nt)
    #pragma unroll
    for (int reg = 0; reg < 4; ++reg) {
        int col = w*32 + nt*16 + m;
        int row = mt*16 + q*4 + reg;
        outC[(size_t)(rowbase + row)*128 + col] = f2b(acc2[mt][nt][reg] + b2_l[col]);
    }
}

// ---------------------------------------------------------------------------
// fill: scatter (s,d) int2 pairs into dst-sorted slots
// ---------------------------------------------------------------------------
__global__ __launch_bounds__(256) void fill_sorted(
    const int* __restrict__ esi, const int* __restrict__ edi, int E,
    int* __restrict__ nxt, int2* __restrict__ spair)
{
    int i = blockIdx.x*256 + threadIdx.x;
    if (i < E) {
        int s = esi[i], d = edi[i];
        int p = atomicAdd(&nxt[d], 1);
        spair[p] = make_int2(s, d);
    }
}

// ---------------------------------------------------------------------------
// Edge kernel: 64 dst-sorted edges/block.
// X = relu(dpos@dist_w+db) bf16 (trunc) -> K=4 GEMM W1b ->
// H f32 = relu(acc + G) where G = Csrc[s]+Cdst'[d] (Cdst' includes b1) ->
// segmented reduction -> atomicAdd hsum.
// H f32 [64][132] aliases X (rows 0-31) and G (rows 32-63); G rows 32-63 are
// register-staged before being overwritten.
// ---------------------------------------------------------------------------
__global__ __launch_bounds__(256, 4) void edge_kernel(
    const ushort_t* __restrict__ Csrc, const ushort_t* __restrict__ Cdst,
    const float* __restrict__ src_pos, const float* __restrict__ dst_pos,
    const int2* __restrict__ spair, int E,
    const ushort_t* __restrict__ w1bm,
    const float* __restrict__ dist_w, const float* __restrict__ dist_b,
    float* __restrict__ hsum)
{
    __shared__ char pool[34816];        // X bf16 [64][136] @0 ; G bf16 [64][136] @17408 ; H f32 [64][132]
    __shared__ int s_l[64], d_l[64], dv_l[64], bnd_l[64], dofs_l[64];
    __shared__ float dx_l[64], dy_l[64];
    __shared__ float dw0_l[128], dw1_l[128], db_l[128];

    ushort_t* X = (ushort_t*)pool;
    ushort_t* G = (ushort_t*)(pool + 17408);
    float* H = (float*)pool;

    int tid = threadIdx.x, blk = blockIdx.x;

    if (tid < 64) {
        int slot = blk*64 + tid;
        if (slot < E) {
            int2 pr = spair[slot];
            s_l[tid] = pr.x; d_l[tid] = pr.y; dv_l[tid] = pr.y;
            float2 sp = ((const float2*)src_pos)[pr.x];
            float2 dp = ((const float2*)dst_pos)[pr.y];
            dx_l[tid] = sp.x - dp.x;
            dy_l[tid] = sp.y - dp.y;
        } else {
            s_l[tid] = 0; d_l[tid] = -1; dv_l[tid] = 0;
            dx_l[tid] = 0.f; dy_l[tid] = 0.f;
        }
    }
    if (tid < 128) {
        dw0_l[tid] = dist_w[tid];
        dw1_l[tid] = dist_w[128 + tid];
        db_l[tid]  = dist_b[tid];
    }
    __syncthreads();

    // boundary flags + dst offsets (once per tile)
    if (tid < 64) {
        int d = d_l[tid];
        int dn = (tid < 63) ? d_l[tid + 1] : -2;
        bnd_l[tid] = (tid == 31) || (tid == 63) || (dn != d);
        dofs_l[tid] = (d >= 0) ? d*128 : -1;
    }
    // G gather: coalesced uint4 (8 bf16) per lane
    const uint4* cs4 = (const uint4*)Csrc;
    const uint4* cd4 = (const uint4*)Cdst;
    for (int i = tid; i < 1024; i += 256) {
        int r = i >> 4, c = i & 15;
        uint4 a = cs4[(size_t)s_l[r]*16 + c];
        uint4 b = cd4[(size_t)dv_l[r]*16 + c];
        uint4 u;
        u.x = addpack_trunc(a.x, b.x);
        u.y = addpack_trunc(a.y, b.y);
        u.z = addpack_trunc(a.z, b.z);
        u.w = addpack_trunc(a.w, b.w);
        *(uint4*)(G + r*136 + c*8) = u;
    }
    // dist features -> X (trunc pack)
    for (int i = tid; i < 4096; i += 256) {
        int r = i >> 6, j2 = (i & 63)*2;
        float dx = dx_l[r], dy = dy_l[r];
        float v0 = fmaxf(fmaf(dx, dw0_l[j2],   fmaf(dy, dw1_l[j2],   db_l[j2])),   0.f);
        float v1 = fmaxf(fmaf(dx, dw0_l[j2+1], fmaf(dy, dw1_l[j2+1], db_l[j2+1])), 0.f);
        *(uint_t*)(X + r*136 + j2) = pack_trunc(v0, v1);
    }
    __syncthreads();

    int lane = tid & 63, w = tid >> 6, q = lane >> 4, m = lane & 15;
    f32x4 acc[4][2] = {};
    const bhalf8* Wv = (const bhalf8*)w1bm;
    #pragma unroll
    for (int ks = 0; ks < 4; ++ks) {
        bhalf8 bf0 = Wv[((2*w)*4 + ks)*64 + lane];
        bhalf8 bf1 = Wv[((2*w+1)*4 + ks)*64 + lane];
        #pragma unroll
        for (int mt = 0; mt < 4; ++mt) {
            bhalf8 a = *(const bhalf8*)(X + (mt*16 + m)*136 + ks*32 + q*8);
            acc[mt][0] = __builtin_amdgcn_mfma_f32_16x16x32_bf16(a, bf0, acc[mt][0], 0, 0, 0);
            acc[mt][1] = __builtin_amdgcn_mfma_f32_16x16x32_bf16(a, bf1, acc[mt][1], 0, 0, 0);
        }
    }
    __syncthreads();   // X reads done; H may now overwrite X region

    // phase 1: H rows 0-31 (land in dead X region); G rows 0-31 read directly
    #pragma unroll
    for (int mt = 0; mt < 2; ++mt)
    #pragma unroll
    for (int reg = 0; reg < 4; ++reg) {
        int row = mt*16 + q*4 + reg;
        #pragma unroll
        for (int nt = 0; nt < 2; ++nt) {
            int col = w*32 + nt*16 + m;
            H[row*132 + col] = fmaxf(acc[mt][nt][reg] + b2f(G[row*136 + col]), 0.f);
        }
    }
    // phase 2: stage G rows 32-63 into registers
    float gv[2][4][2];
    #pragma unroll
    for (int mt = 2; mt < 4; ++mt)
    #pragma unroll
    for (int reg = 0; reg < 4; ++reg) {
        int row = mt*16 + q*4 + reg;
        #pragma unroll
        for (int nt = 0; nt < 2; ++nt)
            gv[mt-2][reg][nt] = b2f(G[row*136 + w*32 + nt*16 + m]);
    }
    __syncthreads();   // all G-region reads done before H rows 32-63 overwrite it

    // phase 3: H rows 32-63
    #pragma unroll
    for (int mt = 2; mt < 4; ++mt)
    #pragma unroll
    for (int reg = 0; reg < 4; ++reg) {
        int row = mt*16 + q*4 + reg;
        #pragma unroll
        for (int nt = 0; nt < 2; ++nt) {
            int col = w*32 + nt*16 + m;
            H[row*132 + col] = fmaxf(acc[mt][nt][reg] + gv[mt-2][reg][nt], 0.f);
        }
    }
    __syncthreads();

    // segmented reduction: 256 threads = 128 cols x 2 halves of 32 rows
    {
        int j = tid & 127, h = tid >> 7;
        int rend = h*32 + 32;
        float a = 0.f;
        for (int r = h*32; r < rend; ++r) {
            a += H[r*132 + j];
            if (bnd_l[r]) {
                int ofs = dofs_l[r];
                if (ofs >= 0) atomicAdd(&hsum[(size_t)ofs + j], a);
                a = 0.f;
            }
        }
    }
}

// ---------------------------------------------------------------------------
// aggfinal: agg = dst_enc + hsum@W2 + deg*b2 ; LayerNorm ; relu ->
//           out = relu(act@out_w + out_b + dst_feat)
// ---------------------------------------------------------------------------
__global__ __launch_bounds__(256) void aggfinal_kernel(
    const float* __restrict__ hsum, const ushort_t* __restrict__ w2m,
    const float* __restrict__ b2, const int* __restrict__ deg,
    const ushort_t* __restrict__ dst_enc, const float* __restrict__ ln_g,
    const float* __restrict__ ln_b, const ushort_t* __restrict__ moutm,
    const float* __restrict__ out_b, const float* __restrict__ dst_feat,
    float* __restrict__ out)
{
    __shared__ char buf[64*132*4];   // A_l bf16 [64][136] aliased with Y f32 [64][132]
    __shared__ ushort_t act_l[64*136];
    __shared__ float b2_l[128], g_l[128], bl_l[128], ob_l[128];
    __shared__ int deg_l[64];
    __shared__ float ps[64][4], ps2[64][4], mu_l[64], inv_l[64];

    ushort_t* A_l = (ushort_t*)buf;
    float* Y = (float*)buf;
    int tid = threadIdx.x, blk = blockIdx.x;

    const float4* hv = (const float4*)hsum;
    for (int i = tid; i < 1024; i += 256) {
        int r = i >> 4, c = i & 15;
        size_t base = (size_t)(blk*64 + r)*32 + c*2;
        float4 p0 = hv[base], p1 = hv[base + 1];
        uint4 u;
        u.x = (uint_t)f2b(p0.x) | ((uint_t)f2b(p0.y) << 16);
        u.y = (uint_t)f2b(p0.z) | ((uint_t)f2b(p0.w) << 16);
        u.z = (uint_t)f2b(p1.x) | ((uint_t)f2b(p1.y) << 16);
        u.w = (uint_t)f2b(p1.z) | ((uint_t)f2b(p1.w) << 16);
        *(uint4*)(A_l + r*136 + c*8) = u;
    }
    if (tid < 128) { b2_l[tid] = b2[tid]; g_l[tid] = ln_g[tid];
                     bl_l[tid] = ln_b[tid]; ob_l[tid] = out_b[tid]; }
    if (tid < 64) deg_l[tid] = deg[blk*64 + tid];
    __syncthreads();

    int lane = tid & 63, w = tid >> 6, q = lane >> 4, m = lane & 15;
    f32x4 acc[4][2] = {};
    const bhalf8* Wv = (const bhalf8*)w2m;
    #pragma unroll
    for (int ks = 0; ks < 4; ++ks) {
        bhalf8 bf0 = Wv[((2*w)*4 + ks)*64 + lane];
        bhalf8 bf1 = Wv[((2*w+1)*4 + ks)*64 + lane];
        #pragma unroll
        for (int mt = 0; mt < 4; ++mt) {
            bhalf8 a = *(const bhalf8*)(A_l + (mt*16 + m)*136 + ks*32 + q*8);
            acc[mt][0] = __builtin_amdgcn_mfma_f32_16x16x32_bf16(a, bf0, acc[mt][0], 0, 0, 0);
            acc[mt][1] = __builtin_amdgcn_mfma_f32_16x16x32_bf16(a, bf1, acc[mt][1], 0, 0, 0);
        }
    }
    __syncthreads();   // A_l reads done before Y overwrites

    #pragma unroll
    for (int mt = 0; mt < 4; ++mt)
    #pragma unroll
    for (int nt = 0; nt < 2; ++nt)
    #pragma unroll
    for (int reg = 0; reg < 4; ++reg) {
        int col = w*32 + nt*16 + m;
        int rowl = mt*16 + q*4 + reg;
        size_t grow = (size_t)blk*64 + rowl;
        float v = acc[mt][nt][reg] + (float)deg_l[rowl]*b2_l[col] + b2f(dst_enc[grow*128 + col]);
        Y[rowl*132 + col] = v;
    }
    __syncthreads();

    {
        int r = tid >> 2, t4 = tid & 3;
        float s = 0.f, s2 = 0.f;
        for (int jj = 0; jj < 32; ++jj) {
            float v = Y[r*132 + t4*32 + jj];
            s += v; s2 += v*v;
        }
        ps[r][t4] = s; ps2[r][t4] = s2;
    }
    __syncthreads();
    if (tid < 64) {
        int r = tid;
        float sum = ps[r][0] + ps[r][1] + ps[r][2] + ps[r][3];
        float sum2 = ps2[r][0] + ps2[r][1] + ps2[r][2] + ps2[r][3];
        float mu = sum / 128.f;
        float var = sum2 / 128.f - mu*mu;
        mu_l[r] = mu;
        inv_l[r] = 1.0f / sqrtf(var + 1e-5f);
    }
    __syncthreads();
    for (int i = tid; i < 4096; i += 256) {
        int r = i >> 6, j2 = (i & 63)*2;
        float v0 = fmaxf((Y[r*132 + j2]   - mu_l[r]) * inv_l[r] * g_l[j2]   + bl_l[j2],   0.f);
        float v1 = fmaxf((Y[r*132 + j2+1] - mu_l[r]) * inv_l[r] * g_l[j2+1] + bl_l[j2+1], 0.f);
        *(uint_t*)(act_l + r*136 + j2) = (uint_t)f2b(v0) | ((uint_t)f2b(v1) << 16);
    }
    __syncthreads();

    f32x4 acc2[4][2] = {};
    const bhalf8* Wo = (const bhalf8*)moutm;
    #pragma unroll
    for (int ks = 0; ks < 4; ++ks) {
        bhalf8 bf0 = Wo[((2*w)*4 + ks)*64 + lane];
        bhalf8 bf1 = Wo[((2*w+1)*4 + ks)*64 + lane];
        #pragma unroll
        for (int mt = 0; mt < 4; ++mt) {
            bhalf8 a = *(const bhalf8*)(act_l + (mt*16 + m)*136 + ks*32 + q*8);
            acc2[mt][0] = __builtin_amdgcn_mfma_f32_16x16x32_bf16(a, bf0, acc2[mt][0], 0, 0, 0);
            acc2[mt][1] = __builtin_amdgcn_mfma_f32_16x16x32_bf16(a, bf1, acc2[mt][1], 0, 0, 0);
        }
    }
    #pragma unroll
    for (int mt = 0; mt < 4; ++mt)
    #pragma unroll
    for (int nt = 0; nt < 2; ++nt)
    #pragma unroll
    for (int reg = 0; reg < 4; ++reg) {
        int col = w*32 + nt*16 + m;
        size_t row = (size_t)blk*64 + mt*16 + q*4 + reg;
        float v = acc2[mt][nt][reg] + ob_l[col] + dst_feat[row*128 + col];
        out[row*128 + col] = fmaxf(v, 0.f);
    }
}

// ---------------------------------------------------------------------------
extern "C" void kernel_launch(void* const* d_in, const int* in_sizes, int n_in,
                              void* d_out, int out_size, void* d_ws, size_t ws_size,
                              hipStream_t stream)
{
    const float* src_feat = (const float*)d_in[0];
    const float* src_pos  = (const float*)d_in[1];
    const float* dst_feat = (const float*)d_in[2];
    const float* dst_pos  = (const float*)d_in[3];
    const float* src_w    = (const float*)d_in[4];
    const float* src_b    = (const float*)d_in[5];
    const float* dst_w    = (const float*)d_in[6];
    const float* dst_b    = (const float*)d_in[7];
    const float* dist_w   = (const float*)d_in[8];
    const float* dist_b   = (const float*)d_in[9];
    const float* w1       = (const float*)d_in[10];
    const float* b1       = (const float*)d_in[11];
    const float* w2       = (const float*)d_in[12];
    const float* b2       = (const float*)d_in[13];
    const float* ln_g     = (const float*)d_in[14];
    const float* ln_b     = (const float*)d_in[15];
    const float* out_w    = (const float*)d_in[16];
    const float* out_b    = (const float*)d_in[17];
    const int* esi        = (const int*)d_in[18];
    const int* edi        = (const int*)d_in[19];
    int E = in_sizes[18];
    int S = in_sizes[0] / 128;
    int D = in_sizes[2] / 128;

    char* ws = (char*)d_ws;
    size_t off = 0;
    auto alloc = [&](size_t bytes) { char* p = ws + off; off += (bytes + 511) & ~(size_t)511; return p; };
    ushort_t* Csrc    = (ushort_t*)alloc((size_t)S*128*2);
    ushort_t* Cdst    = (ushort_t*)alloc((size_t)D*128*2);
    ushort_t* dst_enc = (ushort_t*)alloc((size_t)D*128*2);
    float*    hsum    = (float*)   alloc((size_t)D*128*4);
    ushort_t* msrc    = (ushort_t*)alloc(128*128*2);
    ushort_t* mdst    = (ushort_t*)alloc(128*128*2);
    ushort_t* m2      = (ushort_t*)alloc(128*128*2);
    ushort_t* mout    = (ushort_t*)alloc(128*128*2);
    ushort_t* m1a     = (ushort_t*)alloc(128*128*2);
    ushort_t* m1b     = (ushort_t*)alloc(128*128*2);
    ushort_t* m1c     = (ushort_t*)alloc(128*128*2);
    int*      deg     = (int*)     alloc((size_t)D*4);
    int*      nxt     = (int*)     alloc((size_t)D*4);
    int2*     spair   = (int2*)    alloc((size_t)E*8);

    hipMemsetAsync(deg, 0, (size_t)D*4, stream);

    int countB = (E + 255)/256;
    int zeroB = 256;
    prep_kernel<<<56 + countB + zeroB, 256, 0, stream>>>(
        src_w, dst_w, w2, out_w, w1,
        msrc, mdst, m2, mout, m1a, m1b, m1c,
        edi, E, deg, hsum, countB, zeroB, D);

    int Sb = S/64, Db = D/64;
    enc2_kernel<<<Sb + Db + 1, 256, 0, stream>>>(
        src_feat, dst_feat, msrc, mdst, m1a, m1c, src_b, dst_b, b1,
        Csrc, Cdst, dst_enc, deg, nxt, D, Sb, Db);

    fill_sorted<<<(E + 255)/256, 256, 0, stream>>>(esi, edi, E, nxt, spair);

    edge_kernel<<<(E + 63)/64, 256, 0, stream>>>(
        Csrc, Cdst, src_pos, dst_pos, spair, E,
        m1b, dist_w, dist_b, hsum);

    aggfinal_kernel<<<Db, 256, 0, stream>>>(
        hsum, m2, b2, deg, dst_enc, ln_g, ln_b,
        mout, out_b, dst_feat, (float*)d_out);
}

// Round 6
// 224.562 us; speedup vs baseline: 1.4255x; 1.0430x over previous
//
#include <hip/hip_runtime.h>

typedef unsigned short ushort_t;
typedef unsigned int uint_t;
typedef short bhalf8 __attribute__((ext_vector_type(8)));
typedef float f32x4 __attribute__((ext_vector_type(4)));

__device__ __forceinline__ float b2f(ushort_t u) {
    union { uint_t i; float f; } v; v.i = ((uint_t)u) << 16; return v.f;
}
__device__ __forceinline__ float u2f(uint_t u) {
    union { uint_t i; float f; } v; v.i = u; return v.f;
}
__device__ __forceinline__ ushort_t f2b(float f) {
    union { float f; uint_t i; } v; v.f = f;
    uint_t r = v.i + 0x7fffu + ((v.i >> 16) & 1u);
    return (ushort_t)(r >> 16);
}
__device__ __forceinline__ uint_t f2u(float f) {
    union { float f; uint_t i; } v; v.f = f; return v.i;
}
// pack two f32 -> bf16x2 by truncation (2 ops)
__device__ __forceinline__ uint_t pack_trunc(float lo, float hi) {
    return (f2u(lo) >> 16) | (f2u(hi) & 0xffff0000u);
}
// packed bf16x2 add with truncation
__device__ __forceinline__ uint_t addpack_trunc(uint_t a, uint_t b) {
    union { uint_t i; float f; } t0, t1, s0, s1;
    t0.i = a << 16;          s0.i = b << 16;
    t1.i = a & 0xffff0000u;  s1.i = b & 0xffff0000u;
    return pack_trunc(t0.f + s0.f, t1.f + s1.f);
}

// ---------------------------------------------------------------------------
// prep kernel: [0,56) weight transform; [56,56+countB) degree count;
// rest: zero hsum.  7 matrices 128x128, KS=4:
//   0:src_w 1:dst_w 2:w2 3:out_w 4:w1a 5:w1b 6:w1c
// ---------------------------------------------------------------------------
__global__ __launch_bounds__(256) void prep_kernel(
    const float* __restrict__ wsrc, const float* __restrict__ wdst,
    const float* __restrict__ w2,   const float* __restrict__ wout,
    const float* __restrict__ w1,
    ushort_t* __restrict__ msrc, ushort_t* __restrict__ mdst,
    ushort_t* __restrict__ m2,   ushort_t* __restrict__ mout,
    ushort_t* __restrict__ m1a,  ushort_t* __restrict__ m1b,
    ushort_t* __restrict__ m1c,
    const int* __restrict__ edi, int E, int* __restrict__ deg,
    float* __restrict__ hsum, int countB, int zeroB, int Dn)
{
    int b = blockIdx.x, tid = threadIdx.x;
    if (b < 56) {
        const float* ins[7] = { wsrc, wdst, w2, wout, w1, w1 + 128*128, w1 + 256*128 };
        ushort_t* outs[7]   = { msrc, mdst, m2, mout, m1a, m1b, m1c };
        int mat = b >> 3;
        const float* in = ins[mat];
        ushort_t* out = outs[mat];
        int flat = (b & 7)*256 + tid;
        int nt = flat >> 8, rem = flat & 255;
        int ks = rem >> 6, lane = rem & 63;
        int q = lane >> 4, m = lane & 15;
        #pragma unroll
        for (int j = 0; j < 8; ++j)
            out[flat*8 + j] = f2b(in[(ks*32 + q*8 + j)*128 + nt*16 + m]);
    } else if (b < 56 + countB) {
        int i = (b - 56)*256 + tid;
        if (i < E) atomicAdd(&deg[edi[i]], 1);
    } else {
        int zb = b - 56 - countB;
        float4* h4 = (float4*)hsum;
        int total4 = Dn*32;
        for (int i = zb*256 + tid; i < total4; i += zeroB*256)
            h4[i] = make_float4(0.f, 0.f, 0.f, 0.f);
    }
}

// ---------------------------------------------------------------------------
// enc2: enc = relu(A@W+b) then C = enc@Wc (+ b1 on dst path)
// block Sb+Db additionally runs the degree scan.
// Global stores routed through LDS -> coalesced uint4.
// ---------------------------------------------------------------------------
__global__ __launch_bounds__(256) void enc2_kernel(
    const float* __restrict__ src_feat, const float* __restrict__ dst_feat,
    const ushort_t* __restrict__ msrc, const ushort_t* __restrict__ mdst,
    const ushort_t* __restrict__ m1a,  const ushort_t* __restrict__ m1c,
    const float* __restrict__ src_b,   const float* __restrict__ dst_b,
    const float* __restrict__ b1,
    ushort_t* __restrict__ Csrc, ushort_t* __restrict__ Cdst,
    ushort_t* __restrict__ dst_enc,
    const int* __restrict__ deg, int* __restrict__ nxt, int Dn,
    int Sb, int Db)
{
    int tid = threadIdx.x, blk = blockIdx.x;

    if (blk == Sb + Db) {                       // ---- scan block ----
        __shared__ int sums[256];
        int per = Dn >> 8;
        const int4* d4 = (const int4*)(deg + tid*per);
        int4 v[16]; int s = 0;
        #pragma unroll
        for (int k = 0; k < 16; ++k) { v[k] = d4[k]; s += v[k].x + v[k].y + v[k].z + v[k].w; }
        sums[tid] = s;
        __syncthreads();
        for (int off = 1; off < 256; off <<= 1) {
            int x = (tid >= off) ? sums[tid - off] : 0;
            __syncthreads();
            sums[tid] += x;
            __syncthreads();
        }
        int run = sums[tid] - s;
        int4* n4 = (int4*)(nxt + tid*per);
        #pragma unroll
        for (int k = 0; k < 16; ++k) {
            int4 o;
            o.x = run; run += v[k].x;
            o.y = run; run += v[k].y;
            o.z = run; run += v[k].z;
            o.w = run; run += v[k].w;
            n4[k] = o;
        }
        return;
    }

    __shared__ ushort_t A_l[64*136];
    __shared__ ushort_t E_l[64*136];
    __shared__ float b_l[128];
    __shared__ float b2_l[128];

    const float* A; const ushort_t *W1m, *W2m; const float* bias;
    ushort_t *outC, *outEnc; int rowbase; const float* bias2;
    if (blk < Sb) { A = src_feat; W1m = msrc; W2m = m1a; bias = src_b;
                    outC = Csrc; outEnc = nullptr; rowbase = blk*64; bias2 = nullptr; }
    else          { A = dst_feat; W1m = mdst; W2m = m1c; bias = dst_b;
                    outC = Cdst; outEnc = dst_enc; rowbase = (blk - Sb)*64; bias2 = b1; }

    const float4* A4 = (const float4*)A;
    for (int i = tid; i < 2048; i += 256) {
        int r = i >> 5, c = i & 31;
        float4 v = A4[(size_t)(rowbase + r)*32 + c];
        uint2 u;
        u.x = pack_trunc(v.x, v.y);
        u.y = pack_trunc(v.z, v.w);
        *(uint2*)(A_l + r*136 + c*4) = u;
    }
    if (tid < 128) { b_l[tid] = bias[tid]; b2_l[tid] = bias2 ? bias2[tid] : 0.f; }
    __syncthreads();

    int lane = tid & 63, w = tid >> 6, q = lane >> 4, m = lane & 15;
    const bhalf8* Wv1 = (const bhalf8*)W1m;
    f32x4 acc[4][2] = {};
    #pragma unroll
    for (int ks = 0; ks < 4; ++ks) {
        bhalf8 bf0 = Wv1[((2*w)*4 + ks)*64 + lane];
        bhalf8 bf1 = Wv1[((2*w+1)*4 + ks)*64 + lane];
        #pragma unroll
        for (int mt = 0; mt < 4; ++mt) {
            bhalf8 a = *(const bhalf8*)(A_l + (mt*16 + m)*136 + ks*32 + q*8);
            acc[mt][0] = __builtin_amdgcn_mfma_f32_16x16x32_bf16(a, bf0, acc[mt][0], 0, 0, 0);
            acc[mt][1] = __builtin_amdgcn_mfma_f32_16x16x32_bf16(a, bf1, acc[mt][1], 0, 0, 0);
        }
    }
    #pragma unroll
    for (int mt = 0; mt < 4; ++mt)
    #pragma unroll
    for (int nt = 0; nt < 2; ++nt)
    #pragma unroll
    for (int reg = 0; reg < 4; ++reg) {
        int col = w*32 + nt*16 + m;
        int row = mt*16 + q*4 + reg;
        E_l[row*136 + col] = f2b(fmaxf(acc[mt][nt][reg] + b_l[col], 0.f));
    }
    __syncthreads();

    if (outEnc) {                                // coalesced dst_enc store
        for (int i = tid; i < 1024; i += 256) {
            int r = i >> 4, c = i & 15;
            ((uint4*)outEnc)[(size_t)(rowbase + r)*16 + c] = *(const uint4*)(E_l + r*136 + c*8);
        }
    }

    const bhalf8* Wv2 = (const bhalf8*)W2m;
    f32x4 acc2[4][2] = {};
    #pragma unroll
    for (int ks = 0; ks < 4; ++ks) {
        bhalf8 bf0 = Wv2[((2*w)*4 + ks)*64 + lane];
        bhalf8 bf1 = Wv2[((2*w+1)*4 + ks)*64 + lane];
        #pragma unroll
        for (int mt = 0; mt < 4; ++mt) {
            bhalf8 a = *(const bhalf8*)(E_l + (mt*16 + m)*136 + ks*32 + q*8);
            acc2[mt][0] = __builtin_amdgcn_mfma_f32_16x16x32_bf16(a, bf0, acc2[mt][0], 0, 0, 0);
            acc2[mt][1] = __builtin_amdgcn_mfma_f32_16x16x32_bf16(a, bf1, acc2[mt][1], 0, 0, 0);
        }
    }
    // A_l is dead (all GEMM1 reads completed before the sync above) -> reuse for outC staging
    #pragma unroll
    for (int mt = 0; mt < 4; ++mt)
    #pragma unroll
    for (int nt = 0; nt < 2; ++nt)
    #pragma unroll
    for (int reg = 0; reg < 4; ++reg) {
        int col = w*32 + nt*16 + m;
        int row = mt*16 + q*4 + reg;
        A_l[row*136 + col] = f2b(acc2[mt][nt][reg] + b2_l[col]);
    }
    __syncthreads();
    for (int i = tid; i < 1024; i += 256) {      // coalesced outC store
        int r = i >> 4, c = i & 15;
        ((uint4*)outC)[(size_t)(rowbase + r)*16 + c] = *(const uint4*)(A_l + r*136 + c*8);
    }
}

// ---------------------------------------------------------------------------
// fill: scatter (s,d) int2 pairs into dst-sorted slots
// ---------------------------------------------------------------------------
__global__ __launch_bounds__(256) void fill_sorted(
    const int* __restrict__ esi, const int* __restrict__ edi, int E,
    int* __restrict__ nxt, int2* __restrict__ spair)
{
    int i = blockIdx.x*256 + threadIdx.x;
    if (i < E) {
        int s = esi[i], d = edi[i];
        int p = atomicAdd(&nxt[d], 1);
        spair[p] = make_int2(s, d);
    }
}

// ---------------------------------------------------------------------------
// Edge kernel: 64 dst-sorted edges/block.
// X = relu(dpos@dist_w+db) bf16 row-major -> K=4 GEMM W1b ->
// raw acc -> Hc bf16 COLUMN-major [128][68] (b64 writes, aliases X) ->
// reduction applies G+relu inline (G row-major LDS, Csrc+Cdst' gather) ->
// segmented atomicAdd into hsum. Boundaries carried as a 64-bit ballot mask.
// ---------------------------------------------------------------------------
__global__ __launch_bounds__(256, 4) void edge_kernel(
    const ushort_t* __restrict__ Csrc, const ushort_t* __restrict__ Cdst,
    const float* __restrict__ src_pos, const float* __restrict__ dst_pos,
    const int2* __restrict__ spair, int E,
    const ushort_t* __restrict__ w1bm,
    const float* __restrict__ dist_w, const float* __restrict__ dist_b,
    float* __restrict__ hsum)
{
    __shared__ char pool[17408];        // X bf16 [64][136]  |  Hc bf16 [128][68]
    __shared__ ushort_t G[64*136];
    __shared__ int s_l[64], d_l[64], dofs_l[64];
    __shared__ uint_t bndmask[2];
    __shared__ float dx_l[64], dy_l[64];
    __shared__ float dw0_l[128], dw1_l[128], db_l[128];

    ushort_t* X  = (ushort_t*)pool;
    ushort_t* Hc = (ushort_t*)pool;

    int tid = threadIdx.x, blk = blockIdx.x;

    if (tid < 64) {
        int slot = blk*64 + tid;
        int s = 0, d = -1;
        float dx = 0.f, dy = 0.f;
        if (slot < E) {
            int2 pr = spair[slot];
            s = pr.x; d = pr.y;
            float2 sp = ((const float2*)src_pos)[s];
            float2 dp = ((const float2*)dst_pos)[d];
            dx = sp.x - dp.x; dy = sp.y - dp.y;
        }
        s_l[tid] = s; d_l[tid] = d;
        dofs_l[tid] = (d >= 0) ? d*128 : -1;
        dx_l[tid] = dx; dy_l[tid] = dy;
    }
    if (tid < 128) {
        dw0_l[tid] = dist_w[tid];
        dw1_l[tid] = dist_w[128 + tid];
        db_l[tid]  = dist_b[tid];
    }
    __syncthreads();

    // boundary ballot (wave 0 only; row == lane)
    if (tid < 64) {
        int d = d_l[tid];
        int dn = (tid < 63) ? d_l[tid + 1] : -2;
        bool bnd = (tid == 31) || (tid == 63) || (dn != d);
        unsigned long long mask = __ballot(bnd);
        if (tid == 0) { bndmask[0] = (uint_t)mask; bndmask[1] = (uint_t)(mask >> 32); }
    }

    // G gather: coalesced uint4 (8 bf16) per lane
    const uint4* cs4 = (const uint4*)Csrc;
    const uint4* cd4 = (const uint4*)Cdst;
    #pragma unroll
    for (int k = 0; k < 4; ++k) {
        int i = tid + k*256;
        int r = i >> 4, c = i & 15;
        uint4 a = cs4[(size_t)s_l[r]*16 + c];
        uint4 b = cd4[(size_t)max(d_l[r], 0)*16 + c];
        uint4 u;
        u.x = addpack_trunc(a.x, b.x);
        u.y = addpack_trunc(a.y, b.y);
        u.z = addpack_trunc(a.z, b.z);
        u.w = addpack_trunc(a.w, b.w);
        *(uint4*)(G + r*136 + c*8) = u;
    }
    // dist features -> X (whole wave writes one row per iter: conflict-free,
    // dx/dy wave-uniform broadcast)
    for (int i = tid; i < 4096; i += 256) {
        int r = i >> 6, j2 = (i & 63)*2;
        float dx = dx_l[r], dy = dy_l[r];
        float v0 = fmaxf(fmaf(dx, dw0_l[j2],   fmaf(dy, dw1_l[j2],   db_l[j2])),   0.f);
        float v1 = fmaxf(fmaf(dx, dw0_l[j2+1], fmaf(dy, dw1_l[j2+1], db_l[j2+1])), 0.f);
        *(uint_t*)(X + r*136 + j2) = pack_trunc(v0, v1);
    }
    __syncthreads();

    int lane = tid & 63, w = tid >> 6, q = lane >> 4, m = lane & 15;
    f32x4 acc[4][2] = {};
    const bhalf8* Wv = (const bhalf8*)w1bm;
    #pragma unroll
    for (int ks = 0; ks < 4; ++ks) {
        bhalf8 bf0 = Wv[((2*w)*4 + ks)*64 + lane];
        bhalf8 bf1 = Wv[((2*w+1)*4 + ks)*64 + lane];
        #pragma unroll
        for (int mt = 0; mt < 4; ++mt) {
            bhalf8 a = *(const bhalf8*)(X + (mt*16 + m)*136 + ks*32 + q*8);
            acc[mt][0] = __builtin_amdgcn_mfma_f32_16x16x32_bf16(a, bf0, acc[mt][0], 0, 0, 0);
            acc[mt][1] = __builtin_amdgcn_mfma_f32_16x16x32_bf16(a, bf1, acc[mt][1], 0, 0, 0);
        }
    }
    __syncthreads();   // X reads done; Hc may overwrite

    // raw acc -> Hc column-major, b64 per (mt,nt)
    #pragma unroll
    for (int mt = 0; mt < 4; ++mt)
    #pragma unroll
    for (int nt = 0; nt < 2; ++nt) {
        int col = w*32 + nt*16 + m;
        int row0 = mt*16 + q*4;
        uint2 u;
        u.x = pack_trunc(acc[mt][nt][0], acc[mt][nt][1]);
        u.y = pack_trunc(acc[mt][nt][2], acc[mt][nt][3]);
        *(uint2*)(Hc + col*68 + row0) = u;
    }
    __syncthreads();

    // segmented reduction: 256 threads = 128 cols x 2 halves of 32 rows;
    // h = relu(Hc + G) computed inline; boundary mask wave-uniform
    {
        int j = tid & 127, h = tid >> 7;
        uint_t mask = bndmask[h];
        const ushort_t* Hcol = Hc + j*68 + h*32;
        int rbase = h*32;
        float a = 0.f;
        #pragma unroll
        for (int k8 = 0; k8 < 8; ++k8) {
            uint2 hp = *(const uint2*)(Hcol + k8*4);
            float hv[4];
            hv[0] = u2f(hp.x << 16);
            hv[1] = u2f(hp.x & 0xffff0000u);
            hv[2] = u2f(hp.y << 16);
            hv[3] = u2f(hp.y & 0xffff0000u);
            #pragma unroll
            for (int t = 0; t < 4; ++t) {
                int r = rbase + k8*4 + t;
                float g = b2f(G[r*136 + j]);
                a += fmaxf(hv[t] + g, 0.f);
                if ((mask >> (k8*4 + t)) & 1u) {
                    int ofs = dofs_l[r];
                    if (ofs >= 0) atomicAdd(&hsum[(size_t)ofs + j], a);
                    a = 0.f;
                }
            }
        }
    }
}

// ---------------------------------------------------------------------------
// aggfinal: agg = dst_enc + hsum@W2 + deg*b2 ; LayerNorm ; relu ->
//           out = relu(act@out_w + out_b + dst_feat)
// ---------------------------------------------------------------------------
__global__ __launch_bounds__(256) void aggfinal_kernel(
    const float* __restrict__ hsum, const ushort_t* __restrict__ w2m,
    const float* __restrict__ b2, const int* __restrict__ deg,
    const ushort_t* __restrict__ dst_enc, const float* __restrict__ ln_g,
    const float* __restrict__ ln_b, const ushort_t* __restrict__ moutm,
    const float* __restrict__ out_b, const float* __restrict__ dst_feat,
    float* __restrict__ out)
{
    __shared__ char buf[64*132*4];   // A_l bf16 [64][136] aliased with Y f32 [64][132]
    __shared__ ushort_t act_l[64*136];
    __shared__ float b2_l[128], g_l[128], bl_l[128], ob_l[128];
    __shared__ int deg_l[64];
    __shared__ float ps[64][4], ps2[64][4], mu_l[64], inv_l[64];

    ushort_t* A_l = (ushort_t*)buf;
    float* Y = (float*)buf;
    int tid = threadIdx.x, blk = blockIdx.x;

    const float4* hv = (const float4*)hsum;
    for (int i = tid; i < 1024; i += 256) {
        int r = i >> 4, c = i & 15;
        size_t base = (size_t)(blk*64 + r)*32 + c*2;
        float4 p0 = hv[base], p1 = hv[base + 1];
        uint4 u;
        u.x = pack_trunc(p0.x, p0.y);
        u.y = pack_trunc(p0.z, p0.w);
        u.z = pack_trunc(p1.x, p1.y);
        u.w = pack_trunc(p1.z, p1.w);
        *(uint4*)(A_l + r*136 + c*8) = u;
    }
    if (tid < 128) { b2_l[tid] = b2[tid]; g_l[tid] = ln_g[tid];
                     bl_l[tid] = ln_b[tid]; ob_l[tid] = out_b[tid]; }
    if (tid < 64) deg_l[tid] = deg[blk*64 + tid];
    __syncthreads();

    int lane = tid & 63, w = tid >> 6, q = lane >> 4, m = lane & 15;
    f32x4 acc[4][2] = {};
    const bhalf8* Wv = (const bhalf8*)w2m;
    #pragma unroll
    for (int ks = 0; ks < 4; ++ks) {
        bhalf8 bf0 = Wv[((2*w)*4 + ks)*64 + lane];
        bhalf8 bf1 = Wv[((2*w+1)*4 + ks)*64 + lane];
        #pragma unroll
        for (int mt = 0; mt < 4; ++mt) {
            bhalf8 a = *(const bhalf8*)(A_l + (mt*16 + m)*136 + ks*32 + q*8);
            acc[mt][0] = __builtin_amdgcn_mfma_f32_16x16x32_bf16(a, bf0, acc[mt][0], 0, 0, 0);
            acc[mt][1] = __builtin_amdgcn_mfma_f32_16x16x32_bf16(a, bf1, acc[mt][1], 0, 0, 0);
        }
    }
    __syncthreads();   // A_l reads done before Y overwrites

    #pragma unroll
    for (int mt = 0; mt < 4; ++mt)
    #pragma unroll
    for (int nt = 0; nt < 2; ++nt)
    #pragma unroll
    for (int reg = 0; reg < 4; ++reg) {
        int col = w*32 + nt*16 + m;
        int rowl = mt*16 + q*4 + reg;
        size_t grow = (size_t)blk*64 + rowl;
        float v = acc[mt][nt][reg] + (float)deg_l[rowl]*b2_l[col] + b2f(dst_enc[grow*128 + col]);
        Y[rowl*132 + col] = v;
    }
    __syncthreads();

    {
        int r = tid >> 2, t4 = tid & 3;
        float s = 0.f, s2 = 0.f;
        for (int jj = 0; jj < 32; ++jj) {
            float v = Y[r*132 + t4*32 + jj];
            s += v; s2 += v*v;
        }
        ps[r][t4] = s; ps2[r][t4] = s2;
    }
    __syncthreads();
    if (tid < 64) {
        int r = tid;
        float sum = ps[r][0] + ps[r][1] + ps[r][2] + ps[r][3];
        float sum2 = ps2[r][0] + ps2[r][1] + ps2[r][2] + ps2[r][3];
        float mu = sum / 128.f;
        float var = sum2 / 128.f - mu*mu;
        mu_l[r] = mu;
        inv_l[r] = 1.0f / sqrtf(var + 1e-5f);
    }
    __syncthreads();
    for (int i = tid; i < 4096; i += 256) {
        int r = i >> 6, j2 = (i & 63)*2;
        float v0 = fmaxf((Y[r*132 + j2]   - mu_l[r]) * inv_l[r] * g_l[j2]   + bl_l[j2],   0.f);
        float v1 = fmaxf((Y[r*132 + j2+1] - mu_l[r]) * inv_l[r] * g_l[j2+1] + bl_l[j2+1], 0.f);
        *(uint_t*)(act_l + r*136 + j2) = (uint_t)f2b(v0) | ((uint_t)f2b(v1) << 16);
    }
    __syncthreads();

    f32x4 acc2[4][2] = {};
    const bhalf8* Wo = (const bhalf8*)moutm;
    #pragma unroll
    for (int ks = 0; ks < 4; ++ks) {
        bhalf8 bf0 = Wo[((2*w)*4 + ks)*64 + lane];
        bhalf8 bf1 = Wo[((2*w+1)*4 + ks)*64 + lane];
        #pragma unroll
        for (int mt = 0; mt < 4; ++mt) {
            bhalf8 a = *(const bhalf8*)(act_l + (mt*16 + m)*136 + ks*32 + q*8);
            acc2[mt][0] = __builtin_amdgcn_mfma_f32_16x16x32_bf16(a, bf0, acc2[mt][0], 0, 0, 0);
            acc2[mt][1] = __builtin_amdgcn_mfma_f32_16x16x32_bf16(a, bf1, acc2[mt][1], 0, 0, 0);
        }
    }
    #pragma unroll
    for (int mt = 0; mt < 4; ++mt)
    #pragma unroll
    for (int nt = 0; nt < 2; ++nt)
    #pragma unroll
    for (int reg = 0; reg < 4; ++reg) {
        int col = w*32 + nt*16 + m;
        size_t row = (size_t)blk*64 + mt*16 + q*4 + reg;
        float v = acc2[mt][nt][reg] + ob_l[col] + dst_feat[row*128 + col];
        out[row*128 + col] = fmaxf(v, 0.f);
    }
}

// ---------------------------------------------------------------------------
extern "C" void kernel_launch(void* const* d_in, const int* in_sizes, int n_in,
                              void* d_out, int out_size, void* d_ws, size_t ws_size,
                              hipStream_t stream)
{
    const float* src_feat = (const float*)d_in[0];
    const float* src_pos  = (const float*)d_in[1];
    const float* dst_feat = (const float*)d_in[2];
    const float* dst_pos  = (const float*)d_in[3];
    const float* src_w    = (const float*)d_in[4];
    const float* src_b    = (const float*)d_in[5];
    const float* dst_w    = (const float*)d_in[6];
    const float* dst_b    = (const float*)d_in[7];
    const float* dist_w   = (const float*)d_in[8];
    const float* dist_b   = (const float*)d_in[9];
    const float* w1       = (const float*)d_in[10];
    const float* b1       = (const float*)d_in[11];
    const float* w2       = (const float*)d_in[12];
    const float* b2       = (const float*)d_in[13];
    const float* ln_g     = (const float*)d_in[14];
    const float* ln_b     = (const float*)d_in[15];
    const float* out_w    = (const float*)d_in[16];
    const float* out_b    = (const float*)d_in[17];
    const int* esi        = (const int*)d_in[18];
    const int* edi        = (const int*)d_in[19];
    int E = in_sizes[18];
    int S = in_sizes[0] / 128;
    int D = in_sizes[2] / 128;

    char* ws = (char*)d_ws;
    size_t off = 0;
    auto alloc = [&](size_t bytes) { char* p = ws + off; off += (bytes + 511) & ~(size_t)511; return p; };
    ushort_t* Csrc    = (ushort_t*)alloc((size_t)S*128*2);
    ushort_t* Cdst    = (ushort_t*)alloc((size_t)D*128*2);
    ushort_t* dst_enc = (ushort_t*)alloc((size_t)D*128*2);
    float*    hsum    = (float*)   alloc((size_t)D*128*4);
    ushort_t* msrc    = (ushort_t*)alloc(128*128*2);
    ushort_t* mdst    = (ushort_t*)alloc(128*128*2);
    ushort_t* m2      = (ushort_t*)alloc(128*128*2);
    ushort_t* mout    = (ushort_t*)alloc(128*128*2);
    ushort_t* m1a     = (ushort_t*)alloc(128*128*2);
    ushort_t* m1b     = (ushort_t*)alloc(128*128*2);
    ushort_t* m1c     = (ushort_t*)alloc(128*128*2);
    int*      deg     = (int*)     alloc((size_t)D*4);
    int*      nxt     = (int*)     alloc((size_t)D*4);
    int2*     spair   = (int2*)    alloc((size_t)E*8);

    hipMemsetAsync(deg, 0, (size_t)D*4, stream);

    int countB = (E + 255)/256;
    int zeroB = 256;
    prep_kernel<<<56 + countB + zeroB, 256, 0, stream>>>(
        src_w, dst_w, w2, out_w, w1,
        msrc, mdst, m2, mout, m1a, m1b, m1c,
        edi, E, deg, hsum, countB, zeroB, D);

    int Sb = S/64, Db = D/64;
    enc2_kernel<<<Sb + Db + 1, 256, 0, stream>>>(
        src_feat, dst_feat, msrc, mdst, m1a, m1c, src_b, dst_b, b1,
        Csrc, Cdst, dst_enc, deg, nxt, D, Sb, Db);

    fill_sorted<<<(E + 255)/256, 256, 0, stream>>>(esi, edi, E, nxt, spair);

    edge_kernel<<<(E + 63)/64, 256, 0, stream>>>(
        Csrc, Cdst, src_pos, dst_pos, spair, E,
        m1b, dist_w, dist_b, hsum);

    aggfinal_kernel<<<Db, 256, 0, stream>>>(
        hsum, m2, b2, deg, dst_enc, ln_g, ln_b,
        mout, out_b, dst_feat, (float*)d_out);
}